// Round 5
// baseline (860.444 us; speedup 1.0000x reference)
//
#include <hip/hip_runtime.h>

#define D_MODEL 1024
#define ROWS    32      // rows per group
#define NG      4       // groups per persistent block
#define BT      512     // threads per block (8 waves)
#define EPS_LN  1e-5f

typedef _Float16 f16x8 __attribute__((ext_vector_type(8)));
typedef _Float16 f16x4 __attribute__((ext_vector_type(4)));
typedef float    f32x4 __attribute__((ext_vector_type(4)));

// lgkm-only barrier: LDS-consistent, leaves global loads/stores in flight
#define BAR() do { asm volatile("s_waitcnt lgkmcnt(0)" ::: "memory"); \
                   __builtin_amdgcn_s_barrier(); } while (0)

// ---- workspace layout (bytes) ----
#define WS_CNT   0                        // u32[64]   histogram
#define WS_B1P   256                      // f32[256]  b1' = b1 + beta @ W1^T
#define WS_CT    1280                     // f32[80]   score offsets (beta dot sig/csig)
#define WS_FH    4096                     // f16x8 [21][32][64]  gamma-folded B hi
#define WS_FL    (4096 + 688128)          // f16x8 [21][32][64]  gamma-folded B lo
#define WS_NEED  (4096 + 2 * 688128)

// tiles 0..15 : W1' columns (16 cols each)   -> gelu/W2 path
// tiles 16..19: gamma*sign(dirs) (64 tiles)  -> tile scores
// tile  20    : gamma*csig (8 cols used)     -> cluster scores

__global__ void prep_kernel(const float* __restrict__ W1,
                            const float* __restrict__ dirs,
                            const float* __restrict__ gamma,
                            const float* __restrict__ beta,
                            const float* __restrict__ b1,
                            char* __restrict__ wsb, int useT) {
    const int b = blockIdx.x, tid = threadIdx.x;
    if (b < 168) {                         // B fragments (21 x 32 x 64 lanes)
        if (!useT) return;
        const int gid = b * 256 + tid;
        const int ct = gid >> 11, ks = (gid >> 6) & 31, l = gid & 63;
        const int c16 = l & 15, kb = ks * 32 + ((l >> 4) << 3);
        f16x8 h, lo;
#pragma unroll
        for (int i = 0; i < 8; ++i) {
            const int k = kb + i;
            const float g = gamma[k];
            float v;
            if (ct < 16) {
                v = g * W1[(ct * 16 + c16) * 1024 + k];
            } else if (ct < 20) {
                const float d = dirs[((ct - 16) * 16 + c16) * 1024 + k];
                v = g * (float)((d > 0.f) - (d < 0.f));
            } else {
                if (c16 < 8) {
                    int s = 0;
                    for (int t = 0; t < 8; ++t) {
                        const float d = dirs[(c16 * 8 + t) * 1024 + k];
                        s += (d > 0.f) - (d < 0.f);
                    }
                    v = g * (float)((s > 0) - (s < 0));
                } else v = 0.f;
            }
            const _Float16 hh = (_Float16)v;
            h[i] = hh; lo[i] = (_Float16)(v - (float)hh);
        }
        *(f16x8*)(wsb + WS_FH + (size_t)gid * 16) = h;
        *(f16x8*)(wsb + WS_FL + (size_t)gid * 16) = lo;
    } else if (b < 184) {                  // b1' (16 cols per block)
        __shared__ float red[256];
        const int jl = tid >> 4, sub = tid & 15;
        const int j = (b - 168) * 16 + jl;
        float s = 0.f;
        for (int i = 0; i < 64; ++i) {
            const int k = sub * 64 + i;
            s += beta[k] * W1[j * 1024 + k];
        }
        red[tid] = s;
        __syncthreads();
        if (sub == 0) {
            float t = 0.f;
            for (int p = 0; p < 16; ++p) t += red[jl * 16 + p];
            ((float*)(wsb + WS_B1P))[j] = b1[j] + t;
        }
    } else if (b < 192) {                  // c_t for 64 tiles (8 per block)
        const int t8 = (b - 184) * 8 + (tid >> 5), l32 = tid & 31;
        float s = 0.f;
        for (int i = 0; i < 32; ++i) {
            const int k = l32 * 32 + i;
            const float d = dirs[t8 * 1024 + k];
            s += beta[k] * (float)((d > 0.f) - (d < 0.f));
        }
        s += __shfl_xor(s, 1); s += __shfl_xor(s, 2); s += __shfl_xor(s, 4);
        s += __shfl_xor(s, 8); s += __shfl_xor(s, 16);
        if (l32 == 0) ((float*)(wsb + WS_CT))[t8] = s;
    } else if (b == 192) {                 // c for 8 csig cols
        const int c = tid >> 5, l32 = tid & 31;
        float s = 0.f;
        for (int i = 0; i < 32; ++i) {
            const int k = l32 * 32 + i;
            int ss = 0;
            for (int t = 0; t < 8; ++t) {
                const float d = dirs[(c * 8 + t) * 1024 + k];
                ss += (d > 0.f) - (d < 0.f);
            }
            s += beta[k] * (float)((ss > 0) - (ss < 0));
        }
        s += __shfl_xor(s, 1); s += __shfl_xor(s, 2); s += __shfl_xor(s, 4);
        s += __shfl_xor(s, 8); s += __shfl_xor(s, 16);
        if (l32 == 0) ((float*)(wsb + WS_CT))[64 + c] = s;
    } else {                               // counts + pad of score offsets
        if (tid < 64) ((unsigned*)(wsb + WS_CNT))[tid] = 0u;
        else if (tid < 72) ((float*)(wsb + WS_CT))[72 + (tid - 64)] = 0.f;
    }
}

// ---- B-fragment fetch (fast: ws frags; slow: direct from f32) ----
template <int USET, int NT, int CT0>
__device__ __forceinline__ void loadB(const char* __restrict__ wsb,
                                      const float* __restrict__ W1,
                                      const float* __restrict__ dirs,
                                      const float* __restrict__ gamma,
                                      int ks, int ln, f16x8* bh, f16x8* bl) {
    if (USET) {
        const size_t fo = ((size_t)((CT0 * 32 + ks) * 64 + ln)) * 16;
#pragma unroll
        for (int t = 0; t < NT; ++t) {
            bh[t] = *(const f16x8*)(wsb + WS_FH + fo + (size_t)t * 32 * 64 * 16);
            bl[t] = *(const f16x8*)(wsb + WS_FL + fo + (size_t)t * 32 * 64 * 16);
        }
    } else {
        const int c16 = ln & 15, kb = ks * 32 + ((ln >> 4) << 3);
        float g[8];
#pragma unroll
        for (int i = 0; i < 8; ++i) g[i] = gamma[kb + i];
#pragma unroll
        for (int t = 0; t < NT; ++t) {
            const int ct = CT0 + t;
#pragma unroll
            for (int i = 0; i < 8; ++i) {
                const int k = kb + i;
                float v;
                if (ct < 16) {
                    v = g[i] * W1[(ct * 16 + c16) * 1024 + k];
                } else if (ct < 20) {
                    const float d = dirs[((ct - 16) * 16 + c16) * 1024 + k];
                    v = g[i] * (float)((d > 0.f) - (d < 0.f));
                } else {
                    if (c16 < 8) {
                        int s = 0;
                        for (int tt = 0; tt < 8; ++tt) {
                            const float d = dirs[(c16 * 8 + tt) * 1024 + k];
                            s += (d > 0.f) - (d < 0.f);
                        }
                        v = g[i] * (float)((s > 0) - (s < 0));
                    } else v = 0.f;
                }
                const _Float16 hh = (_Float16)v;
                bh[t][i] = hh; bl[t][i] = (_Float16)(v - (float)hh);
            }
        }
    }
}

template <int NT>
__device__ __forceinline__ void mfma6(const f16x8 (&a)[2][2], const f16x8* bh,
                                      const f16x8* bl, f32x4 (*acc)[2]) {
    __builtin_amdgcn_s_setprio(1);
#pragma unroll
    for (int t = 0; t < NT; ++t) {
        acc[t][0] = __builtin_amdgcn_mfma_f32_16x16x32_f16(a[0][0], bh[t], acc[t][0], 0, 0, 0);
        acc[t][1] = __builtin_amdgcn_mfma_f32_16x16x32_f16(a[1][0], bh[t], acc[t][1], 0, 0, 0);
    }
#pragma unroll
    for (int t = 0; t < NT; ++t) {
        acc[t][0] = __builtin_amdgcn_mfma_f32_16x16x32_f16(a[0][0], bl[t], acc[t][0], 0, 0, 0);
        acc[t][1] = __builtin_amdgcn_mfma_f32_16x16x32_f16(a[1][0], bl[t], acc[t][1], 0, 0, 0);
    }
#pragma unroll
    for (int t = 0; t < NT; ++t) {
        acc[t][0] = __builtin_amdgcn_mfma_f32_16x16x32_f16(a[0][1], bh[t], acc[t][0], 0, 0, 0);
        acc[t][1] = __builtin_amdgcn_mfma_f32_16x16x32_f16(a[1][1], bh[t], acc[t][1], 0, 0, 0);
    }
    __builtin_amdgcn_s_setprio(0);
}

// each wave owns NT column-tiles for BOTH row-tiles (32 rows); no in-loop barriers.
// depth-2 B prefetch (mod-3 bufs), depth-1 A double-buffer; fully unrolled -> static idx.
template <int USET, int NT, int CT0>
__device__ __forceinline__ void runM(const _Float16* __restrict__ xh,
                                     const _Float16* __restrict__ xl,
                                     const char* __restrict__ wsb,
                                     const float* __restrict__ W1,
                                     const float* __restrict__ dirs,
                                     const float* __restrict__ gamma,
                                     const float* __restrict__ W2,
                                     int wv, int ln,
                                     float (*scores)[84], float (*part)[32][2]) {
    const int r16 = ln & 15, kgrp = ln >> 4;
    const int kofs = kgrp << 3, asw = (r16 & 7) << 3;
    const float* b1p = (const float*)(wsb + WS_B1P);
    const float* ctv = (const float*)(wsb + WS_CT);

    f32x4 acc[NT][2];
#pragma unroll
    for (int t = 0; t < NT; ++t) {
        acc[t][0] = (f32x4){0.f, 0.f, 0.f, 0.f};
        acc[t][1] = (f32x4){0.f, 0.f, 0.f, 0.f};
    }
    f16x8 bh[3][NT], bl[3][NT];
    f16x8 a[2][2][2];

#define LDA2(KS, A) { const int cc_ = (((KS) * 32 + kofs) ^ asw); \
                      const int i0_ = r16 * 1024 + cc_, i1_ = (16 + r16) * 1024 + cc_; \
                      A[0][0] = *(const f16x8*)&xh[i0_]; A[0][1] = *(const f16x8*)&xl[i0_]; \
                      A[1][0] = *(const f16x8*)&xh[i1_]; A[1][1] = *(const f16x8*)&xl[i1_]; }

    loadB<USET, NT, CT0>(wsb, W1, dirs, gamma, 0, ln, bh[0], bl[0]);
    loadB<USET, NT, CT0>(wsb, W1, dirs, gamma, 1, ln, bh[1], bl[1]);
    LDA2(0, a[0]);
#pragma unroll
    for (int ks = 0; ks < 32; ++ks) {
        if (ks + 2 < 32)
            loadB<USET, NT, CT0>(wsb, W1, dirs, gamma, ks + 2, ln, bh[(ks + 2) % 3], bl[(ks + 2) % 3]);
        if (ks + 1 < 32)
            LDA2(ks + 1, a[(ks + 1) & 1]);
        mfma6<NT>(a[ks & 1], bh[ks % 3], bl[ks % 3], acc);
    }
#undef LDA2

    // epilogue: gelu+W2 partials for W1 tiles, score dump for sig tiles
    float p0s[2][4] = {{0.f,0.f,0.f,0.f},{0.f,0.f,0.f,0.f}};
    float p1s[2][4] = {{0.f,0.f,0.f,0.f},{0.f,0.f,0.f,0.f}};
#pragma unroll
    for (int t = 0; t < NT; ++t) {
        const int ct = CT0 + t;
        if (ct < 16) {
            const int col = ct * 16 + r16;
            const float b1c = b1p[col], w20 = W2[col], w21 = W2[256 + col];
#pragma unroll
            for (int rt = 0; rt < 2; ++rt)
#pragma unroll
                for (int reg = 0; reg < 4; ++reg) {
                    const float h = acc[t][rt][reg] + b1c;
                    const float gl = 0.5f * h * (1.f + erff(h * 0.70710678118654752f));
                    p0s[rt][reg] += gl * w20; p1s[rt][reg] += gl * w21;
                }
        } else {
            const int sc = (ct - 16) * 16 + r16;
            const float cadd = ctv[sc];
#pragma unroll
            for (int rt = 0; rt < 2; ++rt)
#pragma unroll
                for (int reg = 0; reg < 4; ++reg)
                    scores[rt * 16 + kgrp * 4 + reg][sc] = acc[t][rt][reg] + cadd;
        }
    }
    if (CT0 < 16) {
#pragma unroll
        for (int rt = 0; rt < 2; ++rt)
#pragma unroll
            for (int reg = 0; reg < 4; ++reg) {
                float v0 = p0s[rt][reg], v1 = p1s[rt][reg];
                v0 += __shfl_xor(v0, 1); v0 += __shfl_xor(v0, 2);
                v0 += __shfl_xor(v0, 4); v0 += __shfl_xor(v0, 8);
                v1 += __shfl_xor(v1, 1); v1 += __shfl_xor(v1, 2);
                v1 += __shfl_xor(v1, 4); v1 += __shfl_xor(v1, 8);
                if (r16 == 0) {
                    const int row = rt * 16 + kgrp * 4 + reg;
                    part[wv][row][0] = v0; part[wv][row][1] = v1;
                }
            }
    }
}

template <int USET>
__launch_bounds__(BT, 2)
__global__ void main_kernel(const float* __restrict__ x,
                            const float* __restrict__ gamma,
                            const float* __restrict__ beta,
                            const float* __restrict__ W1,
                            const float* __restrict__ b1,
                            const float* __restrict__ W2,
                            const float* __restrict__ b2,
                            const float* __restrict__ spline,
                            const float* __restrict__ sscale,
                            const float* __restrict__ dirs,
                            const float* __restrict__ oscale,
                            float* __restrict__ out,
                            float* __restrict__ out_tile,
                            float* __restrict__ out_comp,
                            char* __restrict__ wsb) {
    __shared__ __align__(16) _Float16 xh[ROWS * 1024];
    __shared__ __align__(16) _Float16 xl[ROWS * 1024];
    __shared__ float scores[ROWS][84];
    __shared__ float part[8][ROWS][2];
    __shared__ float mu_s[ROWS], sstd_s[ROWS];
    __shared__ float comp_ab[ROWS][2], sval_s[ROWS];
    __shared__ int   tidx_s[ROWS];

    const int tid = threadIdx.x, wv = tid >> 6, ln = tid & 63;
    const int grp0 = blockIdx.x * NG;
    const float os = oscale[0];

    // prologue: load x(group 0) into registers
    float4 xq[4][4];
    {
        const int row0 = grp0 * ROWS;
#pragma unroll
        for (int q = 0; q < 4; ++q) {
            const float4* xp = (const float4*)(x + (size_t)(row0 + wv * 4 + q) * D_MODEL);
#pragma unroll
            for (int i = 0; i < 4; ++i) xq[q][i] = xp[ln + 64 * i];
        }
    }

    for (int g = 0; g < NG; ++g) {
        const int row0 = (grp0 + g) * ROWS;

        // ---------- phase 1: LN from registers -> f16 hi/lo LDS ----------
#pragma unroll
        for (int q = 0; q < 4; ++q) {
            const int rl = wv * 4 + q;
            float s = 0.f;
#pragma unroll
            for (int i = 0; i < 4; ++i)
                s += xq[q][i].x + xq[q][i].y + xq[q][i].z + xq[q][i].w;
#pragma unroll
            for (int o = 1; o < 64; o <<= 1) s += __shfl_xor(s, o);
            const float mu = s * (1.f / 1024.f);
            float v = 0.f;
#pragma unroll
            for (int i = 0; i < 4; ++i) {
                float dx;
                dx = xq[q][i].x - mu; v += dx * dx;
                dx = xq[q][i].y - mu; v += dx * dx;
                dx = xq[q][i].z - mu; v += dx * dx;
                dx = xq[q][i].w - mu; v += dx * dx;
            }
#pragma unroll
            for (int o = 1; o < 64; o <<= 1) v += __shfl_xor(v, o);
            const float sstd = sqrtf(v * (1.f / 1024.f) + EPS_LN);
            const float rstd = 1.f / sstd;
            if (ln == 0) { mu_s[rl] = mu; sstd_s[rl] = sstd; }
            const int sw = (rl & 7) << 3;
#pragma unroll
            for (int i = 0; i < 4; ++i) {
                const float o0 = (xq[q][i].x - mu) * rstd, o1 = (xq[q][i].y - mu) * rstd;
                const float o2 = (xq[q][i].z - mu) * rstd, o3 = (xq[q][i].w - mu) * rstd;
                f16x4 hv, lv;
                _Float16 t0 = (_Float16)o0; hv[0] = t0; lv[0] = (_Float16)(o0 - (float)t0);
                _Float16 t1 = (_Float16)o1; hv[1] = t1; lv[1] = (_Float16)(o1 - (float)t1);
                _Float16 t2 = (_Float16)o2; hv[2] = t2; lv[2] = (_Float16)(o2 - (float)t2);
                _Float16 t3 = (_Float16)o3; hv[3] = t3; lv[3] = (_Float16)(o3 - (float)t3);
                const int k0 = 4 * (ln + 64 * i);
                const int idx = rl * 1024 + (k0 ^ sw);
                *(f16x4*)&xh[idx] = hv;
                *(f16x4*)&xl[idx] = lv;
            }
        }
        BAR();

        // ---------- prefetch x(g+1) into the (now free) registers ----------
        if (g + 1 < NG) {
            const int nrow0 = (grp0 + g + 1) * ROWS;
#pragma unroll
            for (int q = 0; q < 4; ++q) {
                const float4* xp = (const float4*)(x + (size_t)(nrow0 + wv * 4 + q) * D_MODEL);
#pragma unroll
                for (int i = 0; i < 4; ++i) xq[q][i] = xp[ln + 64 * i];
            }
        }

        // ---------- phase M: wave-owned tiles, barrier-free ----------
        if (wv == 0)      runM<USET, 3, 0 >(xh, xl, wsb, W1, dirs, gamma, W2, wv, ln, scores, part);
        else if (wv == 1) runM<USET, 3, 3 >(xh, xl, wsb, W1, dirs, gamma, W2, wv, ln, scores, part);
        else if (wv == 2) runM<USET, 3, 6 >(xh, xl, wsb, W1, dirs, gamma, W2, wv, ln, scores, part);
        else if (wv == 3) runM<USET, 3, 9 >(xh, xl, wsb, W1, dirs, gamma, W2, wv, ln, scores, part);
        else if (wv == 4) runM<USET, 3, 12>(xh, xl, wsb, W1, dirs, gamma, W2, wv, ln, scores, part);
        else if (wv == 5) runM<USET, 2, 15>(xh, xl, wsb, W1, dirs, gamma, W2, wv, ln, scores, part);
        else if (wv == 6) runM<USET, 2, 17>(xh, xl, wsb, W1, dirs, gamma, W2, wv, ln, scores, part);
        else              runM<USET, 2, 19>(xh, xl, wsb, W1, dirs, gamma, W2, wv, ln, scores, part);
        BAR();

        // ---------- selection (tid<32) and comp finalize (tid 64..127) ----------
        unsigned* cntp = (unsigned*)(wsb + WS_CNT);
        if (tid < ROWS) {
            const int r = tid;
            int bc = 0; float bs = scores[r][64];
#pragma unroll
            for (int c = 1; c < 8; ++c) { const float v = scores[r][64 + c]; if (v > bs) { bs = v; bc = c; } }
            int bt = 0; float ts = scores[r][bc * 8];
#pragma unroll
            for (int p = 1; p < 8; ++p) { const float v = scores[r][bc * 8 + p]; if (v > ts) { ts = v; bt = p; } }
            const int ti = bc * 8 + bt;
            tidx_s[r] = ti;
            atomicAdd(&cntp[ti], 1u);
            out_tile[row0 + r] = (float)ti;
        } else if (tid >= 64 && tid < 64 + 2 * ROWS) {
            const int r = (tid - 64) >> 1, cc = tid & 1;
            float s = part[0][r][cc] + part[1][r][cc] + part[2][r][cc] +
                      part[3][r][cc] + part[4][r][cc] + part[5][r][cc] + b2[cc];
            s = tanhf(s);
            comp_ab[r][cc] = s;
            out_comp[(size_t)(row0 + r) * 2 + cc] = s;
        }
        BAR();

        // ---------- spline lookup ----------
        if (tid < ROWS) {
            const int r = tid;
            const float a = comp_ab[r][0], b = comp_ab[r][1];
            int ia = (int)((a + 1.0f) / 2.0f * 16.0f);
            int ib = (int)((b + 1.0f) / 2.0f * 16.0f);
            ia = min(max(ia, 0), 15); ib = min(max(ib, 0), 15);
            const int ti = tidx_s[r];
            const float* cp = spline + ((ti * 16 + ia) * 16 + ib) * 3;
            float c0 = cp[0], c1 = cp[1], c2 = cp[2];
            c0 = (c0 > 0.3f) ? 1.f : ((c0 < -0.3f) ? -1.f : 0.f);
            c1 = (c1 > 0.3f) ? 1.f : ((c1 < -0.3f) ? -1.f : 0.f);
            c2 = (c2 > 0.3f) ? 1.f : ((c2 < -0.3f) ? -1.f : 0.f);
            const float la = (a + 1.0f - (float)ia * 0.125f) * 8.0f;
            const float lb = (b + 1.0f - (float)ib * 0.125f) * 8.0f;
            sval_s[r] = (c0 + c1 * la + c2 * lb) * sscale[ti];
        }
        BAR();

        // ---------- phase 8: out = x + os * sval * directions[tile] (async stores) ----------
#pragma unroll
        for (int q = 0; q < 4; ++q) {
            const int rl = wv * 4 + q, row = row0 + rl;
            const int ti = tidx_s[rl];
            const float s = sval_s[rl] * os;
            const float mu = mu_s[rl], sd = sstd_s[rl];
            const int sw = (rl & 7) << 3;
            const float4* dp = (const float4*)(dirs + (size_t)ti * D_MODEL);
            float4* op = (float4*)(out + (size_t)row * D_MODEL);
#pragma unroll
            for (int i = 0; i < 4; ++i) {
                const int k0 = 4 * (ln + 64 * i);
                const int idx = rl * 1024 + (k0 ^ sw);
                const f16x4 hv = *(const f16x4*)&xh[idx];
                const f16x4 lv = *(const f16x4*)&xl[idx];
                const float4 dv = dp[ln + 64 * i];
                float4 o4;
                o4.x = ((float)hv[0] + (float)lv[0]) * sd + mu + s * dv.x;
                o4.y = ((float)hv[1] + (float)lv[1]) * sd + mu + s * dv.y;
                o4.z = ((float)hv[2] + (float)lv[2]) * sd + mu + s * dv.z;
                o4.w = ((float)hv[3] + (float)lv[3]) * sd + mu + s * dv.w;
                op[ln + 64 * i] = o4;
            }
        }
        BAR();   // xh/xl ds_reads drained; next LN may overwrite LDS
    }
}

__global__ void bal_kernel(const unsigned* __restrict__ counts, float* __restrict__ ob) {
    const int t = threadIdx.x;
    const float d = (float)counts[t] - 512.0f;
    float v = d * d;
#pragma unroll
    for (int o = 1; o < 64; o <<= 1) v += __shfl_xor(v, o);
    if (t == 0) ob[0] = (v * (1.f / 64.f)) / 262144.0f * 0.01f;
}

extern "C" void kernel_launch(void* const* d_in, const int* in_sizes, int n_in,
                              void* d_out, int out_size, void* d_ws, size_t ws_size,
                              hipStream_t stream) {
    const float* x      = (const float*)d_in[0];
    const float* gamma  = (const float*)d_in[1];
    const float* beta   = (const float*)d_in[2];
    const float* W1     = (const float*)d_in[3];
    const float* b1     = (const float*)d_in[4];
    const float* W2     = (const float*)d_in[5];
    const float* b2     = (const float*)d_in[6];
    const float* spline = (const float*)d_in[7];
    const float* sscale = (const float*)d_in[8];
    const float* dirs   = (const float*)d_in[9];
    const float* oscale = (const float*)d_in[10];

    const int nrows = in_sizes[0] / D_MODEL;          // 32768
    float* out      = (float*)d_out;
    float* out_tile = out + (size_t)nrows * D_MODEL;
    float* out_comp = out_tile + nrows;
    float* out_bal  = out_comp + (size_t)nrows * 2;

    char* wsb = (char*)d_ws;
    const int useT = (ws_size >= (size_t)WS_NEED) ? 1 : 0;
    const int nblk = nrows / (ROWS * NG);             // 256 persistent blocks

    prep_kernel<<<194, 256, 0, stream>>>(W1, dirs, gamma, beta, b1, wsb, useT);
    if (useT)
        main_kernel<1><<<nblk, BT, 0, stream>>>(x, gamma, beta, W1, b1, W2, b2,
                                                spline, sscale, dirs, oscale,
                                                out, out_tile, out_comp, wsb);
    else
        main_kernel<0><<<nblk, BT, 0, stream>>>(x, gamma, beta, W1, b1, W2, b2,
                                                spline, sscale, dirs, oscale,
                                                out, out_tile, out_comp, wsb);
    bal_kernel<<<1, 64, 0, stream>>>((const unsigned*)(wsb + WS_CNT), out_bal);
}

// Round 6
// 188.832 us; speedup vs baseline: 4.5567x; 4.5567x over previous
//
#include <hip/hip_runtime.h>

#define D_MODEL 1024
#define ROWS    32      // rows per block
#define BT      512     // threads per block (8 waves)
#define EPS_LN  1e-5f

typedef _Float16 f16x8 __attribute__((ext_vector_type(8)));
typedef _Float16 f16x4 __attribute__((ext_vector_type(4)));
typedef float    f32x4 __attribute__((ext_vector_type(4)));

// ---- workspace layout (bytes) ----
#define WS_CNT   0                        // u32[64]   histogram
#define WS_B1P   256                      // f32[256]  b1' = b1 + beta @ W1^T
#define WS_CT    1280                     // f32[80]   score offsets (beta dot sig/csig)
#define WS_FH    4096                     // f16x8 [21][32][64]  gamma-folded B hi
#define WS_FL    (4096 + 688128)          // f16x8 [21][32][64]  gamma-folded B lo
#define WS_NEED  (4096 + 2 * 688128)

// tiles 0..15 : W1' columns (16 cols each)   -> gelu/W2 path
// tiles 16..19: gamma*sign(dirs) (64 tiles)  -> tile scores
// tile  20    : gamma*csig (8 cols used)     -> cluster scores

__global__ void prep_kernel(const float* __restrict__ W1,
                            const float* __restrict__ dirs,
                            const float* __restrict__ gamma,
                            const float* __restrict__ beta,
                            const float* __restrict__ b1,
                            char* __restrict__ wsb, int useT) {
    const int b = blockIdx.x, tid = threadIdx.x;
    if (b < 168) {                         // B fragments (21 x 32 x 64 lanes)
        if (!useT) return;
        const int gid = b * 256 + tid;
        const int ct = gid >> 11, ks = (gid >> 6) & 31, l = gid & 63;
        const int c16 = l & 15, kb = ks * 32 + ((l >> 4) << 3);
        f16x8 h, lo;
#pragma unroll
        for (int i = 0; i < 8; ++i) {
            const int k = kb + i;
            const float g = gamma[k];
            float v;
            if (ct < 16) {
                v = g * W1[(ct * 16 + c16) * 1024 + k];
            } else if (ct < 20) {
                const float d = dirs[((ct - 16) * 16 + c16) * 1024 + k];
                v = g * (float)((d > 0.f) - (d < 0.f));
            } else {
                if (c16 < 8) {
                    int s = 0;
                    for (int t = 0; t < 8; ++t) {
                        const float d = dirs[(c16 * 8 + t) * 1024 + k];
                        s += (d > 0.f) - (d < 0.f);
                    }
                    v = g * (float)((s > 0) - (s < 0));
                } else v = 0.f;
            }
            const _Float16 hh = (_Float16)v;
            h[i] = hh; lo[i] = (_Float16)(v - (float)hh);
        }
        *(f16x8*)(wsb + WS_FH + (size_t)gid * 16) = h;
        *(f16x8*)(wsb + WS_FL + (size_t)gid * 16) = lo;
    } else if (b < 184) {                  // b1' (16 cols per block)
        __shared__ float red[256];
        const int jl = tid >> 4, sub = tid & 15;
        const int j = (b - 168) * 16 + jl;
        float s = 0.f;
        for (int i = 0; i < 64; ++i) {
            const int k = sub * 64 + i;
            s += beta[k] * W1[j * 1024 + k];
        }
        red[tid] = s;
        __syncthreads();
        if (sub == 0) {
            float t = 0.f;
            for (int p = 0; p < 16; ++p) t += red[jl * 16 + p];
            ((float*)(wsb + WS_B1P))[j] = b1[j] + t;
        }
    } else if (b < 192) {                  // c_t for 64 tiles (8 per block)
        const int t8 = (b - 184) * 8 + (tid >> 5), l32 = tid & 31;
        float s = 0.f;
        for (int i = 0; i < 32; ++i) {
            const int k = l32 * 32 + i;
            const float d = dirs[t8 * 1024 + k];
            s += beta[k] * (float)((d > 0.f) - (d < 0.f));
        }
        s += __shfl_xor(s, 1); s += __shfl_xor(s, 2); s += __shfl_xor(s, 4);
        s += __shfl_xor(s, 8); s += __shfl_xor(s, 16);
        if (l32 == 0) ((float*)(wsb + WS_CT))[t8] = s;
    } else if (b == 192) {                 // c for 8 csig cols
        const int c = tid >> 5, l32 = tid & 31;
        float s = 0.f;
        for (int i = 0; i < 32; ++i) {
            const int k = l32 * 32 + i;
            int ss = 0;
            for (int t = 0; t < 8; ++t) {
                const float d = dirs[(c * 8 + t) * 1024 + k];
                ss += (d > 0.f) - (d < 0.f);
            }
            s += beta[k] * (float)((ss > 0) - (ss < 0));
        }
        s += __shfl_xor(s, 1); s += __shfl_xor(s, 2); s += __shfl_xor(s, 4);
        s += __shfl_xor(s, 8); s += __shfl_xor(s, 16);
        if (l32 == 0) ((float*)(wsb + WS_CT))[64 + c] = s;
    } else {                               // counts + pad of score offsets
        if (tid < 64) ((unsigned*)(wsb + WS_CNT))[tid] = 0u;
        else if (tid < 72) ((float*)(wsb + WS_CT))[72 + (tid - 64)] = 0.f;
    }
}

// ---- B-fragment fetch (fast: ws frags; slow: direct from f32) ----
template <int USET, int NT, int CT0>
__device__ __forceinline__ void loadB(const char* __restrict__ wsb,
                                      const float* __restrict__ W1,
                                      const float* __restrict__ dirs,
                                      const float* __restrict__ gamma,
                                      int ks, int ln, f16x8* bh, f16x8* bl) {
    if (USET) {
        const size_t fo = ((size_t)((CT0 * 32 + ks) * 64 + ln)) * 16;
#pragma unroll
        for (int t = 0; t < NT; ++t) {
            bh[t] = *(const f16x8*)(wsb + WS_FH + fo + (size_t)t * 32 * 64 * 16);
            bl[t] = *(const f16x8*)(wsb + WS_FL + fo + (size_t)t * 32 * 64 * 16);
        }
    } else {
        const int c16 = ln & 15, kb = ks * 32 + ((ln >> 4) << 3);
        float g[8];
#pragma unroll
        for (int i = 0; i < 8; ++i) g[i] = gamma[kb + i];
#pragma unroll
        for (int t = 0; t < NT; ++t) {
            const int ct = CT0 + t;
#pragma unroll
            for (int i = 0; i < 8; ++i) {
                const int k = kb + i;
                float v;
                if (ct < 16) {
                    v = g[i] * W1[(ct * 16 + c16) * 1024 + k];
                } else if (ct < 20) {
                    const float d = dirs[((ct - 16) * 16 + c16) * 1024 + k];
                    v = g[i] * (float)((d > 0.f) - (d < 0.f));
                } else {
                    if (c16 < 8) {
                        int s = 0;
                        for (int tt = 0; tt < 8; ++tt) {
                            const float d = dirs[(c16 * 8 + tt) * 1024 + k];
                            s += (d > 0.f) - (d < 0.f);
                        }
                        v = g[i] * (float)((s > 0) - (s < 0));
                    } else v = 0.f;
                }
                const _Float16 hh = (_Float16)v;
                bh[t][i] = hh; bl[t][i] = (_Float16)(v - (float)hh);
            }
        }
    }
}

template <int NT>
__device__ __forceinline__ void mfma6(const f16x8 (&a)[2][2], const f16x8* bh,
                                      const f16x8* bl, f32x4 (*acc)[2]) {
    __builtin_amdgcn_s_setprio(1);
#pragma unroll
    for (int t = 0; t < NT; ++t) {
        acc[t][0] = __builtin_amdgcn_mfma_f32_16x16x32_f16(a[0][0], bh[t], acc[t][0], 0, 0, 0);
        acc[t][1] = __builtin_amdgcn_mfma_f32_16x16x32_f16(a[1][0], bh[t], acc[t][1], 0, 0, 0);
    }
#pragma unroll
    for (int t = 0; t < NT; ++t) {
        acc[t][0] = __builtin_amdgcn_mfma_f32_16x16x32_f16(a[0][0], bl[t], acc[t][0], 0, 0, 0);
        acc[t][1] = __builtin_amdgcn_mfma_f32_16x16x32_f16(a[1][0], bl[t], acc[t][1], 0, 0, 0);
    }
#pragma unroll
    for (int t = 0; t < NT; ++t) {
        acc[t][0] = __builtin_amdgcn_mfma_f32_16x16x32_f16(a[0][1], bh[t], acc[t][0], 0, 0, 0);
        acc[t][1] = __builtin_amdgcn_mfma_f32_16x16x32_f16(a[1][1], bh[t], acc[t][1], 0, 0, 0);
    }
    __builtin_amdgcn_s_setprio(0);
}

// each wave owns NT column-tiles for BOTH row-tiles (32 rows); no in-loop barriers.
// depth-2 B prefetch (mod-3 register bufs), depth-1 A double-buffer; fully
// unrolled ks loop -> every buffer index is compile-time static (rule #20).
template <int USET, int NT, int CT0>
__device__ __forceinline__ void runM(const _Float16* __restrict__ xh,
                                     const _Float16* __restrict__ xl,
                                     const char* __restrict__ wsb,
                                     const float* __restrict__ W1,
                                     const float* __restrict__ dirs,
                                     const float* __restrict__ gamma,
                                     const float* __restrict__ W2,
                                     int wv, int ln,
                                     float (*scores)[84], float (*part)[32][2]) {
    const int r16 = ln & 15, kgrp = ln >> 4;
    const int kofs = kgrp << 3, asw = (r16 & 7) << 3;
    const float* b1p = (const float*)(wsb + WS_B1P);
    const float* ctv = (const float*)(wsb + WS_CT);

    f32x4 acc[NT][2];
#pragma unroll
    for (int t = 0; t < NT; ++t) {
        acc[t][0] = (f32x4){0.f, 0.f, 0.f, 0.f};
        acc[t][1] = (f32x4){0.f, 0.f, 0.f, 0.f};
    }
    f16x8 bh[3][NT], bl[3][NT];
    f16x8 a[2][2][2];

#define LDA2(KS, A) { const int cc_ = (((KS) * 32 + kofs) ^ asw); \
                      const int i0_ = r16 * 1024 + cc_, i1_ = (16 + r16) * 1024 + cc_; \
                      A[0][0] = *(const f16x8*)&xh[i0_]; A[0][1] = *(const f16x8*)&xl[i0_]; \
                      A[1][0] = *(const f16x8*)&xh[i1_]; A[1][1] = *(const f16x8*)&xl[i1_]; }

    loadB<USET, NT, CT0>(wsb, W1, dirs, gamma, 0, ln, bh[0], bl[0]);
    loadB<USET, NT, CT0>(wsb, W1, dirs, gamma, 1, ln, bh[1], bl[1]);
    LDA2(0, a[0]);
#pragma unroll
    for (int ks = 0; ks < 32; ++ks) {
        if (ks + 2 < 32)
            loadB<USET, NT, CT0>(wsb, W1, dirs, gamma, ks + 2, ln, bh[(ks + 2) % 3], bl[(ks + 2) % 3]);
        if (ks + 1 < 32)
            LDA2(ks + 1, a[(ks + 1) & 1]);
        mfma6<NT>(a[ks & 1], bh[ks % 3], bl[ks % 3], acc);
    }
#undef LDA2

    // epilogue: gelu+W2 partials for W1 tiles, score dump for sig tiles
    float p0s[2][4] = {{0.f,0.f,0.f,0.f},{0.f,0.f,0.f,0.f}};
    float p1s[2][4] = {{0.f,0.f,0.f,0.f},{0.f,0.f,0.f,0.f}};
#pragma unroll
    for (int t = 0; t < NT; ++t) {
        const int ct = CT0 + t;
        if (ct < 16) {
            const int col = ct * 16 + r16;
            const float b1c = b1p[col], w20 = W2[col], w21 = W2[256 + col];
#pragma unroll
            for (int rt = 0; rt < 2; ++rt)
#pragma unroll
                for (int reg = 0; reg < 4; ++reg) {
                    const float h = acc[t][rt][reg] + b1c;
                    const float gl = 0.5f * h * (1.f + erff(h * 0.70710678118654752f));
                    p0s[rt][reg] += gl * w20; p1s[rt][reg] += gl * w21;
                }
        } else {
            const int sc = (ct - 16) * 16 + r16;
            const float cadd = ctv[sc];
#pragma unroll
            for (int rt = 0; rt < 2; ++rt)
#pragma unroll
                for (int reg = 0; reg < 4; ++reg)
                    scores[rt * 16 + kgrp * 4 + reg][sc] = acc[t][rt][reg] + cadd;
        }
    }
    if (CT0 < 16) {
#pragma unroll
        for (int rt = 0; rt < 2; ++rt)
#pragma unroll
            for (int reg = 0; reg < 4; ++reg) {
                float v0 = p0s[rt][reg], v1 = p1s[rt][reg];
                v0 += __shfl_xor(v0, 1); v0 += __shfl_xor(v0, 2);
                v0 += __shfl_xor(v0, 4); v0 += __shfl_xor(v0, 8);
                v1 += __shfl_xor(v1, 1); v1 += __shfl_xor(v1, 2);
                v1 += __shfl_xor(v1, 4); v1 += __shfl_xor(v1, 8);
                if (r16 == 0) {
                    const int row = rt * 16 + kgrp * 4 + reg;
                    part[wv][row][0] = v0; part[wv][row][1] = v1;
                }
            }
    }
}

template <int USET>
__launch_bounds__(BT, 2)
__global__ void main_kernel(const float* __restrict__ x,
                            const float* __restrict__ gamma,
                            const float* __restrict__ beta,
                            const float* __restrict__ W1,
                            const float* __restrict__ b1,
                            const float* __restrict__ W2,
                            const float* __restrict__ b2,
                            const float* __restrict__ spline,
                            const float* __restrict__ sscale,
                            const float* __restrict__ dirs,
                            const float* __restrict__ oscale,
                            float* __restrict__ out,
                            float* __restrict__ out_tile,
                            float* __restrict__ out_comp,
                            char* __restrict__ wsb) {
    __shared__ __align__(16) _Float16 xh[ROWS * 1024];
    __shared__ __align__(16) _Float16 xl[ROWS * 1024];
    __shared__ float scores[ROWS][84];
    __shared__ float part[8][ROWS][2];
    __shared__ float mu_s[ROWS], sstd_s[ROWS];
    __shared__ float comp_ab[ROWS][2], sval_s[ROWS];
    __shared__ int   tidx_s[ROWS];

    const int tid = threadIdx.x, wv = tid >> 6, ln = tid & 63;
    const int row0 = blockIdx.x * ROWS;

    // ---------- phase 1: LayerNorm stats; x-hat = (x-mu)*rstd -> f16 hi/lo LDS ----------
    for (int q = 0; q < 4; ++q) {
        const int rl = wv * 4 + q;
        const float4* xp = (const float4*)(x + (size_t)(row0 + rl) * D_MODEL);
        float4 xv[4];
        float s = 0.f;
#pragma unroll
        for (int i = 0; i < 4; ++i) {
            xv[i] = xp[ln + 64 * i];
            s += xv[i].x + xv[i].y + xv[i].z + xv[i].w;
        }
#pragma unroll
        for (int o = 1; o < 64; o <<= 1) s += __shfl_xor(s, o);
        const float mu = s * (1.f / 1024.f);
        float v = 0.f;
#pragma unroll
        for (int i = 0; i < 4; ++i) {
            float dx;
            dx = xv[i].x - mu; v += dx * dx;
            dx = xv[i].y - mu; v += dx * dx;
            dx = xv[i].z - mu; v += dx * dx;
            dx = xv[i].w - mu; v += dx * dx;
        }
#pragma unroll
        for (int o = 1; o < 64; o <<= 1) v += __shfl_xor(v, o);
        const float sstd = sqrtf(v * (1.f / 1024.f) + EPS_LN);
        const float rstd = 1.f / sstd;
        if (ln == 0) { mu_s[rl] = mu; sstd_s[rl] = sstd; }
        const int sw = (rl & 7) << 3;
#pragma unroll
        for (int i = 0; i < 4; ++i) {
            const float o0 = (xv[i].x - mu) * rstd, o1 = (xv[i].y - mu) * rstd;
            const float o2 = (xv[i].z - mu) * rstd, o3 = (xv[i].w - mu) * rstd;
            f16x4 hv, lv;
            _Float16 t0 = (_Float16)o0; hv[0] = t0; lv[0] = (_Float16)(o0 - (float)t0);
            _Float16 t1 = (_Float16)o1; hv[1] = t1; lv[1] = (_Float16)(o1 - (float)t1);
            _Float16 t2 = (_Float16)o2; hv[2] = t2; lv[2] = (_Float16)(o2 - (float)t2);
            _Float16 t3 = (_Float16)o3; hv[3] = t3; lv[3] = (_Float16)(o3 - (float)t3);
            const int k0 = 4 * (ln + 64 * i);
            const int idx = rl * 1024 + (k0 ^ sw);
            *(f16x4*)&xh[idx] = hv;
            *(f16x4*)&xl[idx] = lv;
        }
    }
    __syncthreads();

    // ---------- phase M: wave-owned tiles, barrier-free ----------
    if (wv == 0)      runM<USET, 3, 0 >(xh, xl, wsb, W1, dirs, gamma, W2, wv, ln, scores, part);
    else if (wv == 1) runM<USET, 3, 3 >(xh, xl, wsb, W1, dirs, gamma, W2, wv, ln, scores, part);
    else if (wv == 2) runM<USET, 3, 6 >(xh, xl, wsb, W1, dirs, gamma, W2, wv, ln, scores, part);
    else if (wv == 3) runM<USET, 3, 9 >(xh, xl, wsb, W1, dirs, gamma, W2, wv, ln, scores, part);
    else if (wv == 4) runM<USET, 3, 12>(xh, xl, wsb, W1, dirs, gamma, W2, wv, ln, scores, part);
    else if (wv == 5) runM<USET, 2, 15>(xh, xl, wsb, W1, dirs, gamma, W2, wv, ln, scores, part);
    else if (wv == 6) runM<USET, 2, 17>(xh, xl, wsb, W1, dirs, gamma, W2, wv, ln, scores, part);
    else              runM<USET, 2, 19>(xh, xl, wsb, W1, dirs, gamma, W2, wv, ln, scores, part);
    __syncthreads();

    // ---------- selection (tid<32) and comp finalize (tid 64..127) ----------
    unsigned* cntp = (unsigned*)(wsb + WS_CNT);
    if (tid < ROWS) {
        const int r = tid;
        int bc = 0; float bs = scores[r][64];
#pragma unroll
        for (int c = 1; c < 8; ++c) { const float v = scores[r][64 + c]; if (v > bs) { bs = v; bc = c; } }
        int bt = 0; float ts = scores[r][bc * 8];
#pragma unroll
        for (int p = 1; p < 8; ++p) { const float v = scores[r][bc * 8 + p]; if (v > ts) { ts = v; bt = p; } }
        const int ti = bc * 8 + bt;
        tidx_s[r] = ti;
        atomicAdd(&cntp[ti], 1u);
        out_tile[row0 + r] = (float)ti;
    } else if (tid >= 64 && tid < 64 + 2 * ROWS) {
        const int r = (tid - 64) >> 1, cc = tid & 1;
        float s = part[0][r][cc] + part[1][r][cc] + part[2][r][cc] +
                  part[3][r][cc] + part[4][r][cc] + part[5][r][cc] + b2[cc];
        s = tanhf(s);
        comp_ab[r][cc] = s;
        out_comp[(size_t)(row0 + r) * 2 + cc] = s;
    }
    __syncthreads();

    // ---------- spline lookup ----------
    if (tid < ROWS) {
        const int r = tid;
        const float a = comp_ab[r][0], b = comp_ab[r][1];
        int ia = (int)((a + 1.0f) / 2.0f * 16.0f);
        int ib = (int)((b + 1.0f) / 2.0f * 16.0f);
        ia = min(max(ia, 0), 15); ib = min(max(ib, 0), 15);
        const int ti = tidx_s[r];
        const float* cp = spline + ((ti * 16 + ia) * 16 + ib) * 3;
        float c0 = cp[0], c1 = cp[1], c2 = cp[2];
        c0 = (c0 > 0.3f) ? 1.f : ((c0 < -0.3f) ? -1.f : 0.f);
        c1 = (c1 > 0.3f) ? 1.f : ((c1 < -0.3f) ? -1.f : 0.f);
        c2 = (c2 > 0.3f) ? 1.f : ((c2 < -0.3f) ? -1.f : 0.f);
        const float la = (a + 1.0f - (float)ia * 0.125f) * 8.0f;
        const float lb = (b + 1.0f - (float)ib * 0.125f) * 8.0f;
        sval_s[r] = (c0 + c1 * la + c2 * lb) * sscale[ti];
    }
    __syncthreads();

    // ---------- phase 8: out = x + output_scale * sval * directions[tile] ----------
    const float os = oscale[0];
    for (int q = 0; q < 4; ++q) {
        const int rl = wv * 4 + q, row = row0 + rl;
        const int ti = tidx_s[rl];
        const float s = sval_s[rl] * os;
        const float mu = mu_s[rl], sd = sstd_s[rl];
        const int sw = (rl & 7) << 3;
        const float4* dp = (const float4*)(dirs + (size_t)ti * D_MODEL);
        float4* op = (float4*)(out + (size_t)row * D_MODEL);
#pragma unroll
        for (int i = 0; i < 4; ++i) {
            const int k0 = 4 * (ln + 64 * i);
            const int idx = rl * 1024 + (k0 ^ sw);
            const f16x4 hv = *(const f16x4*)&xh[idx];
            const f16x4 lv = *(const f16x4*)&xl[idx];
            const float4 dv = dp[ln + 64 * i];
            float4 o4;
            o4.x = ((float)hv[0] + (float)lv[0]) * sd + mu + s * dv.x;
            o4.y = ((float)hv[1] + (float)lv[1]) * sd + mu + s * dv.y;
            o4.z = ((float)hv[2] + (float)lv[2]) * sd + mu + s * dv.z;
            o4.w = ((float)hv[3] + (float)lv[3]) * sd + mu + s * dv.w;
            op[ln + 64 * i] = o4;
        }
    }
}

__global__ void bal_kernel(const unsigned* __restrict__ counts, float* __restrict__ ob) {
    const int t = threadIdx.x;
    const float d = (float)counts[t] - 512.0f;
    float v = d * d;
#pragma unroll
    for (int o = 1; o < 64; o <<= 1) v += __shfl_xor(v, o);
    if (t == 0) ob[0] = (v * (1.f / 64.f)) / 262144.0f * 0.01f;
}

extern "C" void kernel_launch(void* const* d_in, const int* in_sizes, int n_in,
                              void* d_out, int out_size, void* d_ws, size_t ws_size,
                              hipStream_t stream) {
    const float* x      = (const float*)d_in[0];
    const float* gamma  = (const float*)d_in[1];
    const float* beta   = (const float*)d_in[2];
    const float* W1     = (const float*)d_in[3];
    const float* b1     = (const float*)d_in[4];
    const float* W2     = (const float*)d_in[5];
    const float* b2     = (const float*)d_in[6];
    const float* spline = (const float*)d_in[7];
    const float* sscale = (const float*)d_in[8];
    const float* dirs   = (const float*)d_in[9];
    const float* oscale = (const float*)d_in[10];

    const int nrows = in_sizes[0] / D_MODEL;          // 32768
    float* out      = (float*)d_out;
    float* out_tile = out + (size_t)nrows * D_MODEL;
    float* out_comp = out_tile + nrows;
    float* out_bal  = out_comp + (size_t)nrows * 2;

    char* wsb = (char*)d_ws;
    const int useT = (ws_size >= (size_t)WS_NEED) ? 1 : 0;

    prep_kernel<<<194, 256, 0, stream>>>(W1, dirs, gamma, beta, b1, wsb, useT);
    if (useT)
        main_kernel<1><<<nrows / ROWS, BT, 0, stream>>>(x, gamma, beta, W1, b1, W2, b2,
                                                        spline, sscale, dirs, oscale,
                                                        out, out_tile, out_comp, wsb);
    else
        main_kernel<0><<<nrows / ROWS, BT, 0, stream>>>(x, gamma, beta, W1, b1, W2, b2,
                                                        spline, sscale, dirs, oscale,
                                                        out, out_tile, out_comp, wsb);
    bal_kernel<<<1, 64, 0, stream>>>((const unsigned*)(wsb + WS_CNT), out_bal);
}

// Round 7
// 174.349 us; speedup vs baseline: 4.9352x; 1.0831x over previous
//
#include <hip/hip_runtime.h>

#define D_MODEL 1024
#define ROWS    32      // rows per block
#define BT      1024    // threads per block (16 waves, 4 per SIMD)
#define EPS_LN  1e-5f

typedef _Float16 f16x8 __attribute__((ext_vector_type(8)));
typedef _Float16 f16x4 __attribute__((ext_vector_type(4)));
typedef float    f32x4 __attribute__((ext_vector_type(4)));

// ---- workspace layout (bytes) ----
#define WS_CNT   0                        // u32[64]   histogram
#define WS_B1P   256                      // f32[256]  b1' = b1 + beta @ W1^T
#define WS_CT    1280                     // f32[80]   score offsets (beta dot sig/csig)
#define WS_FH    4096                     // f16x8 [21][32][64]  gamma-folded B hi
#define WS_FL    (4096 + 688128)          // f16x8 [21][32][64]  gamma-folded B lo
#define WS_NEED  (4096 + 2 * 688128)

// tiles 0..15 : W1' columns (16 cols each)   -> gelu/W2 path
// tiles 16..19: gamma*sign(dirs) (64 tiles)  -> tile scores
// tile  20    : gamma*csig (8 cols used)     -> cluster scores

__global__ void prep_kernel(const float* __restrict__ W1,
                            const float* __restrict__ dirs,
                            const float* __restrict__ gamma,
                            const float* __restrict__ beta,
                            const float* __restrict__ b1,
                            char* __restrict__ wsb, int useT) {
    const int b = blockIdx.x, tid = threadIdx.x;
    if (b < 168) {                         // B fragments (21 x 32 x 64 lanes)
        if (!useT) return;
        const int gid = b * 256 + tid;
        const int ct = gid >> 11, ks = (gid >> 6) & 31, l = gid & 63;
        const int c16 = l & 15, kb = ks * 32 + ((l >> 4) << 3);
        f16x8 h, lo;
#pragma unroll
        for (int i = 0; i < 8; ++i) {
            const int k = kb + i;
            const float g = gamma[k];
            float v;
            if (ct < 16) {
                v = g * W1[(ct * 16 + c16) * 1024 + k];
            } else if (ct < 20) {
                const float d = dirs[((ct - 16) * 16 + c16) * 1024 + k];
                v = g * (float)((d > 0.f) - (d < 0.f));
            } else {
                if (c16 < 8) {
                    int s = 0;
                    for (int t = 0; t < 8; ++t) {
                        const float d = dirs[(c16 * 8 + t) * 1024 + k];
                        s += (d > 0.f) - (d < 0.f);
                    }
                    v = g * (float)((s > 0) - (s < 0));
                } else v = 0.f;
            }
            const _Float16 hh = (_Float16)v;
            h[i] = hh; lo[i] = (_Float16)(v - (float)hh);
        }
        *(f16x8*)(wsb + WS_FH + (size_t)gid * 16) = h;
        *(f16x8*)(wsb + WS_FL + (size_t)gid * 16) = lo;
    } else if (b < 184) {                  // b1' (16 cols per block)
        __shared__ float red[256];
        const int jl = tid >> 4, sub = tid & 15;
        const int j = (b - 168) * 16 + jl;
        float s = 0.f;
        for (int i = 0; i < 64; ++i) {
            const int k = sub * 64 + i;
            s += beta[k] * W1[j * 1024 + k];
        }
        red[tid] = s;
        __syncthreads();
        if (sub == 0) {
            float t = 0.f;
            for (int p = 0; p < 16; ++p) t += red[jl * 16 + p];
            ((float*)(wsb + WS_B1P))[j] = b1[j] + t;
        }
    } else if (b < 192) {                  // c_t for 64 tiles (8 per block)
        const int t8 = (b - 184) * 8 + (tid >> 5), l32 = tid & 31;
        float s = 0.f;
        for (int i = 0; i < 32; ++i) {
            const int k = l32 * 32 + i;
            const float d = dirs[t8 * 1024 + k];
            s += beta[k] * (float)((d > 0.f) - (d < 0.f));
        }
        s += __shfl_xor(s, 1); s += __shfl_xor(s, 2); s += __shfl_xor(s, 4);
        s += __shfl_xor(s, 8); s += __shfl_xor(s, 16);
        if (l32 == 0) ((float*)(wsb + WS_CT))[t8] = s;
    } else if (b == 192) {                 // c for 8 csig cols
        const int c = tid >> 5, l32 = tid & 31;
        float s = 0.f;
        for (int i = 0; i < 32; ++i) {
            const int k = l32 * 32 + i;
            int ss = 0;
            for (int t = 0; t < 8; ++t) {
                const float d = dirs[(c * 8 + t) * 1024 + k];
                ss += (d > 0.f) - (d < 0.f);
            }
            s += beta[k] * (float)((ss > 0) - (ss < 0));
        }
        s += __shfl_xor(s, 1); s += __shfl_xor(s, 2); s += __shfl_xor(s, 4);
        s += __shfl_xor(s, 8); s += __shfl_xor(s, 16);
        if (l32 == 0) ((float*)(wsb + WS_CT))[64 + c] = s;
    } else {                               // counts + pad of score offsets
        if (tid < 64) ((unsigned*)(wsb + WS_CNT))[tid] = 0u;
        else if (tid < 72) ((float*)(wsb + WS_CT))[72 + (tid - 64)] = 0.f;
    }
}

// ---- B-fragment fetch (fast: ws frags; slow: direct from f32) ----
template <int USET, int NT, int CT0>
__device__ __forceinline__ void loadB(const char* __restrict__ wsb,
                                      const float* __restrict__ W1,
                                      const float* __restrict__ dirs,
                                      const float* __restrict__ gamma,
                                      int ks, int ln, f16x8* bh, f16x8* bl) {
    if (USET) {
        const size_t fo = ((size_t)((CT0 * 32 + ks) * 64 + ln)) * 16;
#pragma unroll
        for (int t = 0; t < NT; ++t) {
            bh[t] = *(const f16x8*)(wsb + WS_FH + fo + (size_t)t * 32 * 64 * 16);
            bl[t] = *(const f16x8*)(wsb + WS_FL + fo + (size_t)t * 32 * 64 * 16);
        }
    } else {
        const int c16 = ln & 15, kb = ks * 32 + ((ln >> 4) << 3);
        float g[8];
#pragma unroll
        for (int i = 0; i < 8; ++i) g[i] = gamma[kb + i];
#pragma unroll
        for (int t = 0; t < NT; ++t) {
            const int ct = CT0 + t;
#pragma unroll
            for (int i = 0; i < 8; ++i) {
                const int k = kb + i;
                float v;
                if (ct < 16) {
                    v = g[i] * W1[(ct * 16 + c16) * 1024 + k];
                } else if (ct < 20) {
                    const float d = dirs[((ct - 16) * 16 + c16) * 1024 + k];
                    v = g[i] * (float)((d > 0.f) - (d < 0.f));
                } else {
                    if (c16 < 8) {
                        int s = 0;
                        for (int tt = 0; tt < 8; ++tt) {
                            const float d = dirs[(c16 * 8 + tt) * 1024 + k];
                            s += (d > 0.f) - (d < 0.f);
                        }
                        v = g[i] * (float)((s > 0) - (s < 0));
                    } else v = 0.f;
                }
                const _Float16 hh = (_Float16)v;
                bh[t][i] = hh; bl[t][i] = (_Float16)(v - (float)hh);
            }
        }
    }
}

template <int NT>
__device__ __forceinline__ void mfma6(const f16x8 (&a)[2][2], const f16x8* bh,
                                      const f16x8* bl, f32x4 (*acc)[2]) {
    __builtin_amdgcn_s_setprio(1);
#pragma unroll
    for (int t = 0; t < NT; ++t) {
        acc[t][0] = __builtin_amdgcn_mfma_f32_16x16x32_f16(a[0][0], bh[t], acc[t][0], 0, 0, 0);
        acc[t][1] = __builtin_amdgcn_mfma_f32_16x16x32_f16(a[1][0], bh[t], acc[t][1], 0, 0, 0);
    }
#pragma unroll
    for (int t = 0; t < NT; ++t) {
        acc[t][0] = __builtin_amdgcn_mfma_f32_16x16x32_f16(a[0][0], bl[t], acc[t][0], 0, 0, 0);
        acc[t][1] = __builtin_amdgcn_mfma_f32_16x16x32_f16(a[1][0], bl[t], acc[t][1], 0, 0, 0);
    }
#pragma unroll
    for (int t = 0; t < NT; ++t) {
        acc[t][0] = __builtin_amdgcn_mfma_f32_16x16x32_f16(a[0][1], bh[t], acc[t][0], 0, 0, 0);
        acc[t][1] = __builtin_amdgcn_mfma_f32_16x16x32_f16(a[1][1], bh[t], acc[t][1], 0, 0, 0);
    }
    __builtin_amdgcn_s_setprio(0);
}

// each wave owns NT column-tiles for BOTH 16-row tiles (32 rows); barrier-free,
// depth-1 double-buffered B and A (depth-2 proven neutral in round 6).
template <int USET, int NT, int CT0>
__device__ __forceinline__ void runM(const _Float16* __restrict__ xh,
                                     const _Float16* __restrict__ xl,
                                     const char* __restrict__ wsb,
                                     const float* __restrict__ W1,
                                     const float* __restrict__ dirs,
                                     const float* __restrict__ gamma,
                                     const float* __restrict__ W2,
                                     int wv, int ln,
                                     float (*scores)[84], float (*part)[32][2]) {
    const int r16 = ln & 15, kgrp = ln >> 4;
    const int kofs = kgrp << 3, asw = (r16 & 7) << 3;
    const float* b1p = (const float*)(wsb + WS_B1P);
    const float* ctv = (const float*)(wsb + WS_CT);

    f32x4 acc[NT][2];
#pragma unroll
    for (int t = 0; t < NT; ++t) {
        acc[t][0] = (f32x4){0.f, 0.f, 0.f, 0.f};
        acc[t][1] = (f32x4){0.f, 0.f, 0.f, 0.f};
    }
    f16x8 bh0[NT], bl0[NT], bh1[NT], bl1[NT];
    f16x8 a0[2][2], a1[2][2];

#define LDA2(KS, A) { const int cc_ = (((KS) * 32 + kofs) ^ asw); \
                      const int i0_ = r16 * 1024 + cc_, i1_ = (16 + r16) * 1024 + cc_; \
                      A[0][0] = *(const f16x8*)&xh[i0_]; A[0][1] = *(const f16x8*)&xl[i0_]; \
                      A[1][0] = *(const f16x8*)&xh[i1_]; A[1][1] = *(const f16x8*)&xl[i1_]; }

    loadB<USET, NT, CT0>(wsb, W1, dirs, gamma, 0, ln, bh0, bl0);
    LDA2(0, a0);
    for (int ks = 0; ks < 32; ks += 2) {
        loadB<USET, NT, CT0>(wsb, W1, dirs, gamma, ks + 1, ln, bh1, bl1);
        LDA2(ks + 1, a1);
        mfma6<NT>(a0, bh0, bl0, acc);
        if (ks + 2 < 32) {
            loadB<USET, NT, CT0>(wsb, W1, dirs, gamma, ks + 2, ln, bh0, bl0);
            LDA2(ks + 2, a0);
        }
        mfma6<NT>(a1, bh1, bl1, acc);
    }
#undef LDA2

    // epilogue: gelu+W2 partials for W1 tiles, score dump for sig tiles
    float p0s[2][4] = {{0.f,0.f,0.f,0.f},{0.f,0.f,0.f,0.f}};
    float p1s[2][4] = {{0.f,0.f,0.f,0.f},{0.f,0.f,0.f,0.f}};
#pragma unroll
    for (int t = 0; t < NT; ++t) {
        const int ct = CT0 + t;
        if (ct < 16) {
            const int col = ct * 16 + r16;
            const float b1c = b1p[col], w20 = W2[col], w21 = W2[256 + col];
#pragma unroll
            for (int rt = 0; rt < 2; ++rt)
#pragma unroll
                for (int reg = 0; reg < 4; ++reg) {
                    const float h = acc[t][rt][reg] + b1c;
                    const float gl = 0.5f * h * (1.f + erff(h * 0.70710678118654752f));
                    p0s[rt][reg] += gl * w20; p1s[rt][reg] += gl * w21;
                }
        } else {
            const int sc = (ct - 16) * 16 + r16;
            const float cadd = ctv[sc];
#pragma unroll
            for (int rt = 0; rt < 2; ++rt)
#pragma unroll
                for (int reg = 0; reg < 4; ++reg)
                    scores[rt * 16 + kgrp * 4 + reg][sc] = acc[t][rt][reg] + cadd;
        }
    }
    if (CT0 < 16) {
#pragma unroll
        for (int rt = 0; rt < 2; ++rt)
#pragma unroll
            for (int reg = 0; reg < 4; ++reg) {
                float v0 = p0s[rt][reg], v1 = p1s[rt][reg];
                v0 += __shfl_xor(v0, 1); v0 += __shfl_xor(v0, 2);
                v0 += __shfl_xor(v0, 4); v0 += __shfl_xor(v0, 8);
                v1 += __shfl_xor(v1, 1); v1 += __shfl_xor(v1, 2);
                v1 += __shfl_xor(v1, 4); v1 += __shfl_xor(v1, 8);
                if (r16 == 0) {
                    const int row = rt * 16 + kgrp * 4 + reg;
                    part[wv][row][0] = v0; part[wv][row][1] = v1;
                }
            }
    }
}

template <int USET>
__launch_bounds__(BT, 1)
__global__ void main_kernel(const float* __restrict__ x,
                            const float* __restrict__ gamma,
                            const float* __restrict__ beta,
                            const float* __restrict__ W1,
                            const float* __restrict__ b1,
                            const float* __restrict__ W2,
                            const float* __restrict__ b2,
                            const float* __restrict__ spline,
                            const float* __restrict__ sscale,
                            const float* __restrict__ dirs,
                            const float* __restrict__ oscale,
                            float* __restrict__ out,
                            float* __restrict__ out_tile,
                            float* __restrict__ out_comp,
                            char* __restrict__ wsb) {
    __shared__ __align__(16) _Float16 xh[ROWS * 1024];
    __shared__ __align__(16) _Float16 xl[ROWS * 1024];
    __shared__ float scores[ROWS][84];
    __shared__ float part[16][ROWS][2];
    __shared__ float mu_s[ROWS], sstd_s[ROWS];
    __shared__ float comp_ab[ROWS][2], sval_s[ROWS];
    __shared__ int   tidx_s[ROWS];

    const int tid = threadIdx.x, wv = tid >> 6, ln = tid & 63;
    const int row0 = blockIdx.x * ROWS;

    // ---------- phase 1: LayerNorm stats; x-hat = (x-mu)*rstd -> f16 hi/lo LDS ----------
    for (int q = 0; q < 2; ++q) {
        const int rl = wv * 2 + q;
        const float4* xp = (const float4*)(x + (size_t)(row0 + rl) * D_MODEL);
        float4 xv[4];
        float s = 0.f;
#pragma unroll
        for (int i = 0; i < 4; ++i) {
            xv[i] = xp[ln + 64 * i];
            s += xv[i].x + xv[i].y + xv[i].z + xv[i].w;
        }
#pragma unroll
        for (int o = 1; o < 64; o <<= 1) s += __shfl_xor(s, o);
        const float mu = s * (1.f / 1024.f);
        float v = 0.f;
#pragma unroll
        for (int i = 0; i < 4; ++i) {
            float dx;
            dx = xv[i].x - mu; v += dx * dx;
            dx = xv[i].y - mu; v += dx * dx;
            dx = xv[i].z - mu; v += dx * dx;
            dx = xv[i].w - mu; v += dx * dx;
        }
#pragma unroll
        for (int o = 1; o < 64; o <<= 1) v += __shfl_xor(v, o);
        const float sstd = sqrtf(v * (1.f / 1024.f) + EPS_LN);
        const float rstd = 1.f / sstd;
        if (ln == 0) { mu_s[rl] = mu; sstd_s[rl] = sstd; }
        const int sw = (rl & 7) << 3;
#pragma unroll
        for (int i = 0; i < 4; ++i) {
            const float o0 = (xv[i].x - mu) * rstd, o1 = (xv[i].y - mu) * rstd;
            const float o2 = (xv[i].z - mu) * rstd, o3 = (xv[i].w - mu) * rstd;
            f16x4 hv, lv;
            _Float16 t0 = (_Float16)o0; hv[0] = t0; lv[0] = (_Float16)(o0 - (float)t0);
            _Float16 t1 = (_Float16)o1; hv[1] = t1; lv[1] = (_Float16)(o1 - (float)t1);
            _Float16 t2 = (_Float16)o2; hv[2] = t2; lv[2] = (_Float16)(o2 - (float)t2);
            _Float16 t3 = (_Float16)o3; hv[3] = t3; lv[3] = (_Float16)(o3 - (float)t3);
            const int k0 = 4 * (ln + 64 * i);
            const int idx = rl * 1024 + (k0 ^ sw);
            *(f16x4*)&xh[idx] = hv;
            *(f16x4*)&xl[idx] = lv;
        }
    }
    __syncthreads();

    // ---------- phase M: wave-owned tiles, barrier-free ----------
    // waves 0-4: 2 W1 tiles each (on SIMDs 0,1,2,3,0); waves 5-10: 1 W1 tile;
    // waves 11-14: sig tiles 16-19; wave 15: csig tile 20.
    if (wv == 0)       runM<USET, 2, 0 >(xh, xl, wsb, W1, dirs, gamma, W2, wv, ln, scores, part);
    else if (wv == 1)  runM<USET, 2, 2 >(xh, xl, wsb, W1, dirs, gamma, W2, wv, ln, scores, part);
    else if (wv == 2)  runM<USET, 2, 4 >(xh, xl, wsb, W1, dirs, gamma, W2, wv, ln, scores, part);
    else if (wv == 3)  runM<USET, 2, 6 >(xh, xl, wsb, W1, dirs, gamma, W2, wv, ln, scores, part);
    else if (wv == 4)  runM<USET, 2, 8 >(xh, xl, wsb, W1, dirs, gamma, W2, wv, ln, scores, part);
    else if (wv == 5)  runM<USET, 1, 10>(xh, xl, wsb, W1, dirs, gamma, W2, wv, ln, scores, part);
    else if (wv == 6)  runM<USET, 1, 11>(xh, xl, wsb, W1, dirs, gamma, W2, wv, ln, scores, part);
    else if (wv == 7)  runM<USET, 1, 12>(xh, xl, wsb, W1, dirs, gamma, W2, wv, ln, scores, part);
    else if (wv == 8)  runM<USET, 1, 13>(xh, xl, wsb, W1, dirs, gamma, W2, wv, ln, scores, part);
    else if (wv == 9)  runM<USET, 1, 14>(xh, xl, wsb, W1, dirs, gamma, W2, wv, ln, scores, part);
    else if (wv == 10) runM<USET, 1, 15>(xh, xl, wsb, W1, dirs, gamma, W2, wv, ln, scores, part);
    else if (wv == 11) runM<USET, 1, 16>(xh, xl, wsb, W1, dirs, gamma, W2, wv, ln, scores, part);
    else if (wv == 12) runM<USET, 1, 17>(xh, xl, wsb, W1, dirs, gamma, W2, wv, ln, scores, part);
    else if (wv == 13) runM<USET, 1, 18>(xh, xl, wsb, W1, dirs, gamma, W2, wv, ln, scores, part);
    else if (wv == 14) runM<USET, 1, 19>(xh, xl, wsb, W1, dirs, gamma, W2, wv, ln, scores, part);
    else               runM<USET, 1, 20>(xh, xl, wsb, W1, dirs, gamma, W2, wv, ln, scores, part);
    __syncthreads();

    // ---------- selection (tid<32) and comp finalize (tid 64..127) ----------
    unsigned* cntp = (unsigned*)(wsb + WS_CNT);
    if (tid < ROWS) {
        const int r = tid;
        int bc = 0; float bs = scores[r][64];
#pragma unroll
        for (int c = 1; c < 8; ++c) { const float v = scores[r][64 + c]; if (v > bs) { bs = v; bc = c; } }
        int bt = 0; float ts = scores[r][bc * 8];
#pragma unroll
        for (int p = 1; p < 8; ++p) { const float v = scores[r][bc * 8 + p]; if (v > ts) { ts = v; bt = p; } }
        const int ti = bc * 8 + bt;
        tidx_s[r] = ti;
        atomicAdd(&cntp[ti], 1u);
        out_tile[row0 + r] = (float)ti;
    } else if (tid >= 64 && tid < 64 + 2 * ROWS) {
        const int r = (tid - 64) >> 1, cc = tid & 1;
        float s = b2[cc];
#pragma unroll
        for (int w = 0; w < 11; ++w) s += part[w][r][cc];
        s = tanhf(s);
        comp_ab[r][cc] = s;
        out_comp[(size_t)(row0 + r) * 2 + cc] = s;
    }
    __syncthreads();

    // ---------- spline lookup ----------
    if (tid < ROWS) {
        const int r = tid;
        const float a = comp_ab[r][0], b = comp_ab[r][1];
        int ia = (int)((a + 1.0f) / 2.0f * 16.0f);
        int ib = (int)((b + 1.0f) / 2.0f * 16.0f);
        ia = min(max(ia, 0), 15); ib = min(max(ib, 0), 15);
        const int ti = tidx_s[r];
        const float* cp = spline + ((ti * 16 + ia) * 16 + ib) * 3;
        float c0 = cp[0], c1 = cp[1], c2 = cp[2];
        c0 = (c0 > 0.3f) ? 1.f : ((c0 < -0.3f) ? -1.f : 0.f);
        c1 = (c1 > 0.3f) ? 1.f : ((c1 < -0.3f) ? -1.f : 0.f);
        c2 = (c2 > 0.3f) ? 1.f : ((c2 < -0.3f) ? -1.f : 0.f);
        const float la = (a + 1.0f - (float)ia * 0.125f) * 8.0f;
        const float lb = (b + 1.0f - (float)ib * 0.125f) * 8.0f;
        sval_s[r] = (c0 + c1 * la + c2 * lb) * sscale[ti];
    }
    __syncthreads();

    // ---------- phase 8: out = x + output_scale * sval * directions[tile] ----------
    const float os = oscale[0];
    for (int q = 0; q < 2; ++q) {
        const int rl = wv * 2 + q, row = row0 + rl;
        const int ti = tidx_s[rl];
        const float s = sval_s[rl] * os;
        const float mu = mu_s[rl], sd = sstd_s[rl];
        const int sw = (rl & 7) << 3;
        const float4* dp = (const float4*)(dirs + (size_t)ti * D_MODEL);
        float4* op = (float4*)(out + (size_t)row * D_MODEL);
#pragma unroll
        for (int i = 0; i < 4; ++i) {
            const int k0 = 4 * (ln + 64 * i);
            const int idx = rl * 1024 + (k0 ^ sw);
            const f16x4 hv = *(const f16x4*)&xh[idx];
            const f16x4 lv = *(const f16x4*)&xl[idx];
            const float4 dv = dp[ln + 64 * i];
            float4 o4;
            o4.x = ((float)hv[0] + (float)lv[0]) * sd + mu + s * dv.x;
            o4.y = ((float)hv[1] + (float)lv[1]) * sd + mu + s * dv.y;
            o4.z = ((float)hv[2] + (float)lv[2]) * sd + mu + s * dv.z;
            o4.w = ((float)hv[3] + (float)lv[3]) * sd + mu + s * dv.w;
            op[ln + 64 * i] = o4;
        }
    }
}

__global__ void bal_kernel(const unsigned* __restrict__ counts, float* __restrict__ ob) {
    const int t = threadIdx.x;
    const float d = (float)counts[t] - 512.0f;
    float v = d * d;
#pragma unroll
    for (int o = 1; o < 64; o <<= 1) v += __shfl_xor(v, o);
    if (t == 0) ob[0] = (v * (1.f / 64.f)) / 262144.0f * 0.01f;
}

extern "C" void kernel_launch(void* const* d_in, const int* in_sizes, int n_in,
                              void* d_out, int out_size, void* d_ws, size_t ws_size,
                              hipStream_t stream) {
    const float* x      = (const float*)d_in[0];
    const float* gamma  = (const float*)d_in[1];
    const float* beta   = (const float*)d_in[2];
    const float* W1     = (const float*)d_in[3];
    const float* b1     = (const float*)d_in[4];
    const float* W2     = (const float*)d_in[5];
    const float* b2     = (const float*)d_in[6];
    const float* spline = (const float*)d_in[7];
    const float* sscale = (const float*)d_in[8];
    const float* dirs   = (const float*)d_in[9];
    const float* oscale = (const float*)d_in[10];

    const int nrows = in_sizes[0] / D_MODEL;          // 32768
    float* out      = (float*)d_out;
    float* out_tile = out + (size_t)nrows * D_MODEL;
    float* out_comp = out_tile + nrows;
    float* out_bal  = out_comp + (size_t)nrows * 2;

    char* wsb = (char*)d_ws;
    const int useT = (ws_size >= (size_t)WS_NEED) ? 1 : 0;

    prep_kernel<<<194, 256, 0, stream>>>(W1, dirs, gamma, beta, b1, wsb, useT);
    if (useT)
        main_kernel<1><<<nrows / ROWS, BT, 0, stream>>>(x, gamma, beta, W1, b1, W2, b2,
                                                        spline, sscale, dirs, oscale,
                                                        out, out_tile, out_comp, wsb);
    else
        main_kernel<0><<<nrows / ROWS, BT, 0, stream>>>(x, gamma, beta, W1, b1, W2, b2,
                                                        spline, sscale, dirs, oscale,
                                                        out, out_tile, out_comp, wsb);
    bal_kernel<<<1, 64, 0, stream>>>((const unsigned*)(wsb + WS_CNT), out_bal);
}

// Round 8
// 174.231 us; speedup vs baseline: 4.9385x; 1.0007x over previous
//
#include <hip/hip_runtime.h>

#define D_MODEL 1024
#define ROWS    32      // rows per block
#define BT      1024    // threads per block (16 waves, 4 per SIMD)
#define EPS_LN  1e-5f

typedef _Float16 f16x8 __attribute__((ext_vector_type(8)));
typedef float    f32x4 __attribute__((ext_vector_type(4)));

// ---- workspace layout (bytes) ----
#define WS_CNT   0                        // u32[64]   histogram
#define WS_B1P   256                      // f32[256]  b1' = b1 + beta @ W1^T
#define WS_CT    1280                     // f32[80]   score offsets (beta dot sig/csig)
#define WS_FH    4096                     // f16x8 [21][32][64]  gamma-folded B hi
#define WS_FL    (4096 + 688128)          // f16x8 [21][32][64]  gamma-folded B lo
#define WS_NEED  (4096 + 2 * 688128)

// tiles 0..15 : W1' columns (16 cols each)   -> gelu/W2 path (3 products)
// tiles 16..19: gamma*sign(dirs) (64 tiles)  -> tile scores  (2 products, lo==0)
// tile  20    : gamma*csig (8 cols used)     -> cluster scores (2 products)

__global__ void prep_kernel(const float* __restrict__ W1,
                            const float* __restrict__ dirs,
                            const float* __restrict__ gamma,
                            const float* __restrict__ beta,
                            const float* __restrict__ b1,
                            char* __restrict__ wsb, int useT) {
    const int b = blockIdx.x, tid = threadIdx.x;
    if (b < 168) {                         // B fragments (21 x 32 x 64 lanes)
        if (!useT) return;
        const int gid = b * 256 + tid;
        const int ct = gid >> 11, ks = (gid >> 6) & 31, l = gid & 63;
        const int c16 = l & 15, kb = ks * 32 + ((l >> 4) << 3);
        f16x8 h, lo;
#pragma unroll
        for (int i = 0; i < 8; ++i) {
            const int k = kb + i;
            const float g = gamma[k];
            float v;
            if (ct < 16) {
                v = g * W1[(ct * 16 + c16) * 1024 + k];
            } else if (ct < 20) {
                const float d = dirs[((ct - 16) * 16 + c16) * 1024 + k];
                v = g * (float)((d > 0.f) - (d < 0.f));
            } else {
                if (c16 < 8) {
                    int s = 0;
                    for (int t = 0; t < 8; ++t) {
                        const float d = dirs[(c16 * 8 + t) * 1024 + k];
                        s += (d > 0.f) - (d < 0.f);
                    }
                    v = g * (float)((s > 0) - (s < 0));
                } else v = 0.f;
            }
            const _Float16 hh = (_Float16)v;
            h[i] = hh; lo[i] = (_Float16)(v - (float)hh);
        }
        *(f16x8*)(wsb + WS_FH + (size_t)gid * 16) = h;
        *(f16x8*)(wsb + WS_FL + (size_t)gid * 16) = lo;
    } else if (b < 184) {                  // b1' (16 cols per block)
        __shared__ float red[256];
        const int jl = tid >> 4, sub = tid & 15;
        const int j = (b - 168) * 16 + jl;
        float s = 0.f;
        for (int i = 0; i < 64; ++i) {
            const int k = sub * 64 + i;
            s += beta[k] * W1[j * 1024 + k];
        }
        red[tid] = s;
        __syncthreads();
        if (sub == 0) {
            float t = 0.f;
            for (int p = 0; p < 16; ++p) t += red[jl * 16 + p];
            ((float*)(wsb + WS_B1P))[j] = b1[j] + t;
        }
    } else if (b < 192) {                  // c_t for 64 tiles (8 per block)
        const int t8 = (b - 184) * 8 + (tid >> 5), l32 = tid & 31;
        float s = 0.f;
        for (int i = 0; i < 32; ++i) {
            const int k = l32 * 32 + i;
            const float d = dirs[t8 * 1024 + k];
            s += beta[k] * (float)((d > 0.f) - (d < 0.f));
        }
        s += __shfl_xor(s, 1); s += __shfl_xor(s, 2); s += __shfl_xor(s, 4);
        s += __shfl_xor(s, 8); s += __shfl_xor(s, 16);
        if (l32 == 0) ((float*)(wsb + WS_CT))[t8] = s;
    } else if (b == 192) {                 // c for 8 csig cols
        const int c = tid >> 5, l32 = tid & 31;
        float s = 0.f;
        for (int i = 0; i < 32; ++i) {
            const int k = l32 * 32 + i;
            int ss = 0;
            for (int t = 0; t < 8; ++t) {
                const float d = dirs[(c * 8 + t) * 1024 + k];
                ss += (d > 0.f) - (d < 0.f);
            }
            s += beta[k] * (float)((ss > 0) - (ss < 0));
        }
        s += __shfl_xor(s, 1); s += __shfl_xor(s, 2); s += __shfl_xor(s, 4);
        s += __shfl_xor(s, 8); s += __shfl_xor(s, 16);
        if (l32 == 0) ((float*)(wsb + WS_CT))[64 + c] = s;
    } else {                               // counts + pad of score offsets
        if (tid < 64) ((unsigned*)(wsb + WS_CNT))[tid] = 0u;
        else if (tid < 72) ((float*)(wsb + WS_CT))[72 + (tid - 64)] = 0.f;
    }
}

// ---- W1 B-fragment fetch (hi+lo) ----
template <int USET, int NT, int CT0>
__device__ __forceinline__ void loadBW(const char* __restrict__ wsb,
                                       const float* __restrict__ W1,
                                       const float* __restrict__ gamma,
                                       int ks, int ln, f16x8* bh, f16x8* bl) {
    if (USET) {
        const size_t fo = ((size_t)((CT0 * 32 + ks) * 64 + ln)) * 16;
#pragma unroll
        for (int t = 0; t < NT; ++t) {
            bh[t] = *(const f16x8*)(wsb + WS_FH + fo + (size_t)t * 32 * 64 * 16);
            bl[t] = *(const f16x8*)(wsb + WS_FL + fo + (size_t)t * 32 * 64 * 16);
        }
    } else {
        const int c16 = ln & 15, kb = ks * 32 + ((ln >> 4) << 3);
#pragma unroll
        for (int t = 0; t < NT; ++t) {
#pragma unroll
            for (int i = 0; i < 8; ++i) {
                const int k = kb + i;
                const float v = gamma[k] * W1[((CT0 + t) * 16 + c16) * 1024 + k];
                const _Float16 hh = (_Float16)v;
                bh[t][i] = hh; bl[t][i] = (_Float16)(v - (float)hh);
            }
        }
    }
}

// ---- sig B-fragment fetch (hi only; lo is exactly 0 with gamma=1) ----
template <int USET, int CT0>
__device__ __forceinline__ f16x8 loadBS(const char* __restrict__ wsb,
                                        const float* __restrict__ dirs,
                                        const float* __restrict__ gamma,
                                        int ks, int ln) {
    if (USET) {
        return *(const f16x8*)(wsb + WS_FH + ((size_t)((CT0 * 32 + ks) * 64 + ln)) * 16);
    }
    const int c16 = ln & 15, kb = ks * 32 + ((ln >> 4) << 3);
    f16x8 s;
#pragma unroll
    for (int i = 0; i < 8; ++i) {
        const int k = kb + i;
        float v;
        if (CT0 < 20) {
            const float d = dirs[((CT0 - 16) * 16 + c16) * 1024 + k];
            v = gamma[k] * (float)((d > 0.f) - (d < 0.f));
        } else {
            if (c16 < 8) {
                int ss = 0;
                for (int tt = 0; tt < 8; ++tt) {
                    const float d = dirs[(c16 * 8 + tt) * 1024 + k];
                    ss += (d > 0.f) - (d < 0.f);
                }
                v = gamma[k] * (float)((ss > 0) - (ss < 0));
            } else v = 0.f;
        }
        s[i] = (_Float16)v;
    }
    return s;
}

template <int NT>
__device__ __forceinline__ void mfma3p(const f16x8 (&a)[2][2], const f16x8* bh,
                                       const f16x8* bl, f32x4 (*acc)[2]) {
    __builtin_amdgcn_s_setprio(1);
#pragma unroll
    for (int t = 0; t < NT; ++t) {
        acc[t][0] = __builtin_amdgcn_mfma_f32_16x16x32_f16(a[0][0], bh[t], acc[t][0], 0, 0, 0);
        acc[t][1] = __builtin_amdgcn_mfma_f32_16x16x32_f16(a[1][0], bh[t], acc[t][1], 0, 0, 0);
    }
#pragma unroll
    for (int t = 0; t < NT; ++t) {
        acc[t][0] = __builtin_amdgcn_mfma_f32_16x16x32_f16(a[0][0], bl[t], acc[t][0], 0, 0, 0);
        acc[t][1] = __builtin_amdgcn_mfma_f32_16x16x32_f16(a[1][0], bl[t], acc[t][1], 0, 0, 0);
    }
#pragma unroll
    for (int t = 0; t < NT; ++t) {
        acc[t][0] = __builtin_amdgcn_mfma_f32_16x16x32_f16(a[0][1], bh[t], acc[t][0], 0, 0, 0);
        acc[t][1] = __builtin_amdgcn_mfma_f32_16x16x32_f16(a[1][1], bh[t], acc[t][1], 0, 0, 0);
    }
    __builtin_amdgcn_s_setprio(0);
}

#define LDA2(KS, A) { const int cc_ = (((KS) * 32 + kofs) ^ asw); \
                      const int i0_ = r16 * 1024 + cc_, i1_ = (16 + r16) * 1024 + cc_; \
                      A[0][0] = *(const f16x8*)&xh[i0_]; A[0][1] = *(const f16x8*)&xl[i0_]; \
                      A[1][0] = *(const f16x8*)&xh[i1_]; A[1][1] = *(const f16x8*)&xl[i1_]; }

// W1 tiles: 3 products (ah*bh, ah*bl, al*bh), gelu/W2 epilogue
template <int USET, int NT, int CT0>
__device__ __forceinline__ void runW(const _Float16* __restrict__ xh,
                                     const _Float16* __restrict__ xl,
                                     const char* __restrict__ wsb,
                                     const float* __restrict__ W1,
                                     const float* __restrict__ gamma,
                                     const float* __restrict__ W2,
                                     int wv, int ln, float (*part)[32][2]) {
    const int r16 = ln & 15, kgrp = ln >> 4;
    const int kofs = kgrp << 3, asw = (r16 & 7) << 3;
    const float* b1p = (const float*)(wsb + WS_B1P);

    f32x4 acc[NT][2];
#pragma unroll
    for (int t = 0; t < NT; ++t) {
        acc[t][0] = (f32x4){0.f, 0.f, 0.f, 0.f};
        acc[t][1] = (f32x4){0.f, 0.f, 0.f, 0.f};
    }
    f16x8 bh0[NT], bl0[NT], bh1[NT], bl1[NT];
    f16x8 a0[2][2], a1[2][2];

    loadBW<USET, NT, CT0>(wsb, W1, gamma, 0, ln, bh0, bl0);
    LDA2(0, a0);
    for (int ks = 0; ks < 32; ks += 2) {
        loadBW<USET, NT, CT0>(wsb, W1, gamma, ks + 1, ln, bh1, bl1);
        LDA2(ks + 1, a1);
        mfma3p<NT>(a0, bh0, bl0, acc);
        if (ks + 2 < 32) {
            loadBW<USET, NT, CT0>(wsb, W1, gamma, ks + 2, ln, bh0, bl0);
            LDA2(ks + 2, a0);
        }
        mfma3p<NT>(a1, bh1, bl1, acc);
    }

    // epilogue: gelu + W2 partials
    float p0s[2][4] = {{0.f,0.f,0.f,0.f},{0.f,0.f,0.f,0.f}};
    float p1s[2][4] = {{0.f,0.f,0.f,0.f},{0.f,0.f,0.f,0.f}};
#pragma unroll
    for (int t = 0; t < NT; ++t) {
        const int col = (CT0 + t) * 16 + r16;
        const float b1c = b1p[col], w20 = W2[col], w21 = W2[256 + col];
#pragma unroll
        for (int rt = 0; rt < 2; ++rt)
#pragma unroll
            for (int reg = 0; reg < 4; ++reg) {
                const float h = acc[t][rt][reg] + b1c;
                const float gl = 0.5f * h * (1.f + erff(h * 0.70710678118654752f));
                p0s[rt][reg] += gl * w20; p1s[rt][reg] += gl * w21;
            }
    }
#pragma unroll
    for (int rt = 0; rt < 2; ++rt)
#pragma unroll
        for (int reg = 0; reg < 4; ++reg) {
            float v0 = p0s[rt][reg], v1 = p1s[rt][reg];
            v0 += __shfl_xor(v0, 1); v0 += __shfl_xor(v0, 2);
            v0 += __shfl_xor(v0, 4); v0 += __shfl_xor(v0, 8);
            v1 += __shfl_xor(v1, 1); v1 += __shfl_xor(v1, 2);
            v1 += __shfl_xor(v1, 4); v1 += __shfl_xor(v1, 8);
            if (r16 == 0) {
                const int row = rt * 16 + kgrp * 4 + reg;
                part[wv][row][0] = v0; part[wv][row][1] = v1;
            }
        }
}

// sig tiles: 2 products (ah*bh, al*bh) — bl is exactly 0; score epilogue
template <int USET, int CT0>
__device__ __forceinline__ void runS(const _Float16* __restrict__ xh,
                                     const _Float16* __restrict__ xl,
                                     const char* __restrict__ wsb,
                                     const float* __restrict__ dirs,
                                     const float* __restrict__ gamma,
                                     int ln, float (*scores)[84]) {
    const int r16 = ln & 15, kgrp = ln >> 4;
    const int kofs = kgrp << 3, asw = (r16 & 7) << 3;
    const float* ctv = (const float*)(wsb + WS_CT);

    f32x4 acc[2];
    acc[0] = (f32x4){0.f, 0.f, 0.f, 0.f};
    acc[1] = (f32x4){0.f, 0.f, 0.f, 0.f};
    f16x8 bh0, bh1;
    f16x8 a0[2][2], a1[2][2];

    bh0 = loadBS<USET, CT0>(wsb, dirs, gamma, 0, ln);
    LDA2(0, a0);
    for (int ks = 0; ks < 32; ks += 2) {
        bh1 = loadBS<USET, CT0>(wsb, dirs, gamma, ks + 1, ln);
        LDA2(ks + 1, a1);
        __builtin_amdgcn_s_setprio(1);
        acc[0] = __builtin_amdgcn_mfma_f32_16x16x32_f16(a0[0][0], bh0, acc[0], 0, 0, 0);
        acc[1] = __builtin_amdgcn_mfma_f32_16x16x32_f16(a0[1][0], bh0, acc[1], 0, 0, 0);
        acc[0] = __builtin_amdgcn_mfma_f32_16x16x32_f16(a0[0][1], bh0, acc[0], 0, 0, 0);
        acc[1] = __builtin_amdgcn_mfma_f32_16x16x32_f16(a0[1][1], bh0, acc[1], 0, 0, 0);
        __builtin_amdgcn_s_setprio(0);
        if (ks + 2 < 32) {
            bh0 = loadBS<USET, CT0>(wsb, dirs, gamma, ks + 2, ln);
            LDA2(ks + 2, a0);
        }
        __builtin_amdgcn_s_setprio(1);
        acc[0] = __builtin_amdgcn_mfma_f32_16x16x32_f16(a1[0][0], bh1, acc[0], 0, 0, 0);
        acc[1] = __builtin_amdgcn_mfma_f32_16x16x32_f16(a1[1][0], bh1, acc[1], 0, 0, 0);
        acc[0] = __builtin_amdgcn_mfma_f32_16x16x32_f16(a1[0][1], bh1, acc[0], 0, 0, 0);
        acc[1] = __builtin_amdgcn_mfma_f32_16x16x32_f16(a1[1][1], bh1, acc[1], 0, 0, 0);
        __builtin_amdgcn_s_setprio(0);
    }

    const int sc = (CT0 - 16) * 16 + r16;
    const float cadd = ctv[sc];
#pragma unroll
    for (int rt = 0; rt < 2; ++rt)
#pragma unroll
        for (int reg = 0; reg < 4; ++reg)
            scores[rt * 16 + kgrp * 4 + reg][sc] = acc[rt][reg] + cadd;
}

template <int USET>
__launch_bounds__(BT, 1)
__global__ void main_kernel(const float* __restrict__ x,
                            const float* __restrict__ gamma,
                            const float* __restrict__ beta,
                            const float* __restrict__ W1,
                            const float* __restrict__ b1,
                            const float* __restrict__ W2,
                            const float* __restrict__ b2,
                            const float* __restrict__ spline,
                            const float* __restrict__ sscale,
                            const float* __restrict__ dirs,
                            const float* __restrict__ oscale,
                            float* __restrict__ out,
                            float* __restrict__ out_tile,
                            float* __restrict__ out_comp,
                            char* __restrict__ wsb) {
    __shared__ __align__(16) _Float16 xh[ROWS * 1024];
    __shared__ __align__(16) _Float16 xl[ROWS * 1024];
    __shared__ float scores[ROWS][84];
    __shared__ float part[11][ROWS][2];
    __shared__ float mu_s[ROWS], sstd_s[ROWS];
    __shared__ float sval_s[ROWS];
    __shared__ int   tidx_s[ROWS];

    const int tid = threadIdx.x, wv = tid >> 6, ln = tid & 63;
    const int row0 = blockIdx.x * ROWS;

    // ---------- phase 1: LN; lane owns 8 consecutive k per half; b128 LDS writes ----------
    for (int q = 0; q < 2; ++q) {
        const int rl = wv * 2 + q;
        const float4* xp = (const float4*)(x + (size_t)(row0 + rl) * D_MODEL);
        float4 xa[2][2];
        xa[0][0] = xp[2 * ln];       xa[0][1] = xp[2 * ln + 1];
        xa[1][0] = xp[2 * ln + 128]; xa[1][1] = xp[2 * ln + 129];
        float s = 0.f;
#pragma unroll
        for (int g = 0; g < 2; ++g)
#pragma unroll
            for (int j = 0; j < 2; ++j)
                s += xa[g][j].x + xa[g][j].y + xa[g][j].z + xa[g][j].w;
#pragma unroll
        for (int o = 1; o < 64; o <<= 1) s += __shfl_xor(s, o);
        const float mu = s * (1.f / 1024.f);
        float v = 0.f;
#pragma unroll
        for (int g = 0; g < 2; ++g)
#pragma unroll
            for (int j = 0; j < 2; ++j) {
                float dx;
                dx = xa[g][j].x - mu; v += dx * dx;
                dx = xa[g][j].y - mu; v += dx * dx;
                dx = xa[g][j].z - mu; v += dx * dx;
                dx = xa[g][j].w - mu; v += dx * dx;
            }
#pragma unroll
        for (int o = 1; o < 64; o <<= 1) v += __shfl_xor(v, o);
        const float sstd = sqrtf(v * (1.f / 1024.f) + EPS_LN);
        const float rstd = 1.f / sstd;
        if (ln == 0) { mu_s[rl] = mu; sstd_s[rl] = sstd; }
        const int sw = (rl & 7) << 3;
#pragma unroll
        for (int g = 0; g < 2; ++g) {
            const float f[8] = {xa[g][0].x, xa[g][0].y, xa[g][0].z, xa[g][0].w,
                                xa[g][1].x, xa[g][1].y, xa[g][1].z, xa[g][1].w};
            f16x8 hv, lv;
#pragma unroll
            for (int i = 0; i < 8; ++i) {
                const float o0 = (f[i] - mu) * rstd;
                const _Float16 t0 = (_Float16)o0;
                hv[i] = t0; lv[i] = (_Float16)(o0 - (float)t0);
            }
            const int idx = rl * 1024 + ((8 * ln + 512 * g) ^ sw);
            *(f16x8*)&xh[idx] = hv;
            *(f16x8*)&xl[idx] = lv;
        }
    }
    __syncthreads();

    // ---------- phase M: wave-owned tiles, barrier-free ----------
    if (wv == 0)       runW<USET, 2, 0 >(xh, xl, wsb, W1, gamma, W2, wv, ln, part);
    else if (wv == 1)  runW<USET, 2, 2 >(xh, xl, wsb, W1, gamma, W2, wv, ln, part);
    else if (wv == 2)  runW<USET, 2, 4 >(xh, xl, wsb, W1, gamma, W2, wv, ln, part);
    else if (wv == 3)  runW<USET, 2, 6 >(xh, xl, wsb, W1, gamma, W2, wv, ln, part);
    else if (wv == 4)  runW<USET, 2, 8 >(xh, xl, wsb, W1, gamma, W2, wv, ln, part);
    else if (wv == 5)  runW<USET, 1, 10>(xh, xl, wsb, W1, gamma, W2, wv, ln, part);
    else if (wv == 6)  runW<USET, 1, 11>(xh, xl, wsb, W1, gamma, W2, wv, ln, part);
    else if (wv == 7)  runW<USET, 1, 12>(xh, xl, wsb, W1, gamma, W2, wv, ln, part);
    else if (wv == 8)  runW<USET, 1, 13>(xh, xl, wsb, W1, gamma, W2, wv, ln, part);
    else if (wv == 9)  runW<USET, 1, 14>(xh, xl, wsb, W1, gamma, W2, wv, ln, part);
    else if (wv == 10) runW<USET, 1, 15>(xh, xl, wsb, W1, gamma, W2, wv, ln, part);
    else if (wv == 11) runS<USET, 16>(xh, xl, wsb, dirs, gamma, ln, scores);
    else if (wv == 12) runS<USET, 17>(xh, xl, wsb, dirs, gamma, ln, scores);
    else if (wv == 13) runS<USET, 18>(xh, xl, wsb, dirs, gamma, ln, scores);
    else if (wv == 14) runS<USET, 19>(xh, xl, wsb, dirs, gamma, ln, scores);
    else               runS<USET, 20>(xh, xl, wsb, dirs, gamma, ln, scores);
    __syncthreads();

    // ---------- fused comp + selection + spline (one lane per row) ----------
    unsigned* cntp = (unsigned*)(wsb + WS_CNT);
    if (tid < ROWS) {
        const int r = tid;
        float c0v = b2[0], c1v = b2[1];
#pragma unroll
        for (int w = 0; w < 11; ++w) { c0v += part[w][r][0]; c1v += part[w][r][1]; }
        const float a = tanhf(c0v), b = tanhf(c1v);
        out_comp[(size_t)(row0 + r) * 2 + 0] = a;
        out_comp[(size_t)(row0 + r) * 2 + 1] = b;

        int bc = 0; float bs = scores[r][64];
#pragma unroll
        for (int c = 1; c < 8; ++c) { const float v = scores[r][64 + c]; if (v > bs) { bs = v; bc = c; } }
        int bt = 0; float ts = scores[r][bc * 8];
#pragma unroll
        for (int p = 1; p < 8; ++p) { const float v = scores[r][bc * 8 + p]; if (v > ts) { ts = v; bt = p; } }
        const int ti = bc * 8 + bt;
        tidx_s[r] = ti;
        atomicAdd(&cntp[ti], 1u);
        out_tile[row0 + r] = (float)ti;

        int ia = (int)((a + 1.0f) / 2.0f * 16.0f);
        int ib = (int)((b + 1.0f) / 2.0f * 16.0f);
        ia = min(max(ia, 0), 15); ib = min(max(ib, 0), 15);
        const float* cp = spline + ((ti * 16 + ia) * 16 + ib) * 3;
        float c0 = cp[0], c1 = cp[1], c2 = cp[2];
        c0 = (c0 > 0.3f) ? 1.f : ((c0 < -0.3f) ? -1.f : 0.f);
        c1 = (c1 > 0.3f) ? 1.f : ((c1 < -0.3f) ? -1.f : 0.f);
        c2 = (c2 > 0.3f) ? 1.f : ((c2 < -0.3f) ? -1.f : 0.f);
        const float la = (a + 1.0f - (float)ia * 0.125f) * 8.0f;
        const float lb = (b + 1.0f - (float)ib * 0.125f) * 8.0f;
        sval_s[r] = (c0 + c1 * la + c2 * lb) * sscale[ti];
    }
    __syncthreads();

    // ---------- phase 8: out = x + os*sval*dirs[tile]; b128 LDS reads ----------
    const float os = oscale[0];
    for (int q = 0; q < 2; ++q) {
        const int rl = wv * 2 + q, row = row0 + rl;
        const int ti = tidx_s[rl];
        const float s = sval_s[rl] * os;
        const float mu = mu_s[rl], sd = sstd_s[rl];
        const int sw = (rl & 7) << 3;
        const float4* dp = (const float4*)(dirs + (size_t)ti * D_MODEL);
        float4* op = (float4*)(out + (size_t)row * D_MODEL);
#pragma unroll
        for (int g = 0; g < 2; ++g) {
            const int idx = rl * 1024 + ((8 * ln + 512 * g) ^ sw);
            const f16x8 hv = *(const f16x8*)&xh[idx];
            const f16x8 lv = *(const f16x8*)&xl[idx];
            const float4 d0 = dp[2 * ln + 128 * g];
            const float4 d1 = dp[2 * ln + 1 + 128 * g];
            float4 o0, o1;
            o0.x = ((float)hv[0] + (float)lv[0]) * sd + mu + s * d0.x;
            o0.y = ((float)hv[1] + (float)lv[1]) * sd + mu + s * d0.y;
            o0.z = ((float)hv[2] + (float)lv[2]) * sd + mu + s * d0.z;
            o0.w = ((float)hv[3] + (float)lv[3]) * sd + mu + s * d0.w;
            o1.x = ((float)hv[4] + (float)lv[4]) * sd + mu + s * d1.x;
            o1.y = ((float)hv[5] + (float)lv[5]) * sd + mu + s * d1.y;
            o1.z = ((float)hv[6] + (float)lv[6]) * sd + mu + s * d1.z;
            o1.w = ((float)hv[7] + (float)lv[7]) * sd + mu + s * d1.w;
            op[2 * ln + 128 * g] = o0;
            op[2 * ln + 1 + 128 * g] = o1;
        }
    }
}

__global__ void bal_kernel(const unsigned* __restrict__ counts, float* __restrict__ ob) {
    const int t = threadIdx.x;
    const float d = (float)counts[t] - 512.0f;
    float v = d * d;
#pragma unroll
    for (int o = 1; o < 64; o <<= 1) v += __shfl_xor(v, o);
    if (t == 0) ob[0] = (v * (1.f / 64.f)) / 262144.0f * 0.01f;
}

extern "C" void kernel_launch(void* const* d_in, const int* in_sizes, int n_in,
                              void* d_out, int out_size, void* d_ws, size_t ws_size,
                              hipStream_t stream) {
    const float* x      = (const float*)d_in[0];
    const float* gamma  = (const float*)d_in[1];
    const float* beta   = (const float*)d_in[2];
    const float* W1     = (const float*)d_in[3];
    const float* b1     = (const float*)d_in[4];
    const float* W2     = (const float*)d_in[5];
    const float* b2     = (const float*)d_in[6];
    const float* spline = (const float*)d_in[7];
    const float* sscale = (const float*)d_in[8];
    const float* dirs   = (const float*)d_in[9];
    const float* oscale = (const float*)d_in[10];

    const int nrows = in_sizes[0] / D_MODEL;          // 32768
    float* out      = (float*)d_out;
    float* out_tile = out + (size_t)nrows * D_MODEL;
    float* out_comp = out_tile + nrows;
    float* out_bal  = out_comp + (size_t)nrows * 2;

    char* wsb = (char*)d_ws;
    const int useT = (ws_size >= (size_t)WS_NEED) ? 1 : 0;

    prep_kernel<<<194, 256, 0, stream>>>(W1, dirs, gamma, beta, b1, wsb, useT);
    if (useT)
        main_kernel<1><<<nrows / ROWS, BT, 0, stream>>>(x, gamma, beta, W1, b1, W2, b2,
                                                        spline, sscale, dirs, oscale,
                                                        out, out_tile, out_comp, wsb);
    else
        main_kernel<0><<<nrows / ROWS, BT, 0, stream>>>(x, gamma, beta, W1, b1, W2, b2,
                                                        spline, sscale, dirs, oscale,
                                                        out, out_tile, out_comp, wsb);
    bal_kernel<<<1, 64, 0, stream>>>((const unsigned*)(wsb + WS_CNT), out_bal);
}